// Round 10
// baseline (6798.250 us; speedup 1.0000x reference)
//
#include <hip/hip_runtime.h>
#include <math.h>

// D_MODEL=1024, N_HEADS=16, D_HEAD=64, QLEN=512, MLEN=512, KLEN=1024, BATCH=8

typedef short bf16x8 __attribute__((ext_vector_type(8)));
typedef float f32x4 __attribute__((ext_vector_type(4)));

union FragU { uint4 u; bf16x8 h; };

// split two fp32 into packed bf16-hi (truncated) and bf16-lo (exact residual, truncated)
__device__ inline void split2(float x0, float x1, unsigned& hi, unsigned& lo) {
    unsigned u0 = __float_as_uint(x0), u1 = __float_as_uint(x1);
    float h0 = __uint_as_float(u0 & 0xffff0000u);
    float h1 = __uint_as_float(u1 & 0xffff0000u);
    unsigned l0 = __float_as_uint(x0 - h0), l1 = __float_as_uint(x1 - h1);
    hi = (u0 >> 16) | (u1 & 0xffff0000u);
    lo = (l0 >> 16) | (l1 & 0xffff0000u);
}

// coherent (agent-scope, cache-bypassing) 8B load/store
__device__ __forceinline__ unsigned long long ld_coh64(const void* p) {
    return __hip_atomic_load((const unsigned long long*)p, __ATOMIC_RELAXED,
                             __HIP_MEMORY_SCOPE_AGENT);
}
__device__ __forceinline__ void st_coh64(void* p, unsigned long long v) {
    __hip_atomic_store((unsigned long long*)p, v, __ATOMIC_RELAXED,
                       __HIP_MEMORY_SCOPE_AGENT);
}

// ---------------------------------------------------------------------------
// Weight prep for GEMMs (unchanged).
// ---------------------------------------------------------------------------
template<bool TR>
__global__ __launch_bounds__(256) void prep_w(
    const float* __restrict__ W, unsigned* __restrict__ out, int Nr, int K, int ldw)
{
    int idx = blockIdx.x * 256 + threadIdx.x;
    int cpr = K >> 3;
    if (idx >= Nr * cpr) return;
    int n, c;
    if (TR) { n = idx % Nr; c = idx / Nr; }
    else    { c = idx % cpr; n = idx / cpr; }
    int kt = c >> 2, j = c & 3;
    int k = kt * 32 + j * 8;
    float x[8];
    #pragma unroll
    for (int i = 0; i < 8; ++i)
        x[i] = TR ? W[(size_t)(k + i) * ldw + n] : W[(size_t)n * ldw + k + i];
    unsigned h[4], l[4];
    split2(x[0], x[1], h[0], l[0]);
    split2(x[2], x[3], h[1], l[1]);
    split2(x[4], x[5], h[2], l[2]);
    split2(x[6], x[7], h[3], l[3]);
    unsigned* base = out + (size_t)n * K + kt * 32;
    *(uint4*)(base + (((2 * j) ^ (n & 7)) * 4))     = make_uint4(h[0], h[1], h[2], h[3]);
    *(uint4*)(base + (((2 * j + 1) ^ (n & 7)) * 4)) = make_uint4(l[0], l[1], l[2], l[3]);
}

// ---------------------------------------------------------------------------
// Split-bf16 MFMA GEMM (unchanged; verified rounds 1-9).
// ---------------------------------------------------------------------------
template<int AMODE, bool BIAS>
__global__ __launch_bounds__(256) void gemm_mfma(
    const float* __restrict__ A, const float* __restrict__ A2,
    const unsigned* __restrict__ Bp, const float* __restrict__ bias,
    float* __restrict__ C, int M, int N, int K, int lda, int ldc)
{
    __shared__ uint4 Ab[1024];
    __shared__ uint4 Bb[1024];
    int tid = threadIdx.x;
    int lane = tid & 63, wid = tid >> 6;
    int wr = wid >> 1, wc = wid & 1;
    int n0 = blockIdx.x * 128, m0 = blockIdx.y * 128;
    int r15 = lane & 15, s = lane >> 4;

    f32x4 acc[4][4];
    #pragma unroll
    for (int i = 0; i < 4; ++i)
        #pragma unroll
        for (int j = 0; j < 4; ++j) acc[i][j] = 0.0f;

    for (int kt = 0; kt < (K >> 5); ++kt) {
        int k0 = kt * 32;
        #pragma unroll
        for (int q = 0; q < 2; ++q) {
            int idx = q * 256 + tid;
            int row = idx >> 2, j = idx & 3;
            const float* ap;
            if (AMODE == 1) {
                int gm = m0 + row;
                ap = (gm < 4096) ? (A + (size_t)gm * lda) : (A2 + (size_t)(gm - 4096) * lda);
            } else {
                ap = A + (size_t)(m0 + row) * lda;
            }
            float4 x0 = *(const float4*)(ap + k0 + j * 8);
            float4 x1 = *(const float4*)(ap + k0 + j * 8 + 4);
            unsigned h[4], l[4];
            split2(x0.x, x0.y, h[0], l[0]);
            split2(x0.z, x0.w, h[1], l[1]);
            split2(x1.x, x1.y, h[2], l[2]);
            split2(x1.z, x1.w, h[3], l[3]);
            Ab[row * 8 + (((2 * j) ^ (row & 7)))]     = make_uint4(h[0], h[1], h[2], h[3]);
            Ab[row * 8 + (((2 * j + 1) ^ (row & 7)))] = make_uint4(l[0], l[1], l[2], l[3]);
        }
        #pragma unroll
        for (int q = 0; q < 4; ++q) {
            int idx = q * 256 + tid;
            int row = idx >> 3, slot = idx & 7;
            Bb[idx] = *(const uint4*)(Bp + (size_t)(n0 + row) * K + k0 + slot * 4);
        }
        __syncthreads();
        FragU ahi[4], alo[4], bhi[4], blo[4];
        #pragma unroll
        for (int f = 0; f < 4; ++f) {
            int ar = wr * 64 + f * 16 + r15;
            ahi[f].u = Ab[ar * 8 + ((2 * s) ^ (ar & 7))];
            alo[f].u = Ab[ar * 8 + ((2 * s + 1) ^ (ar & 7))];
            int br = wc * 64 + f * 16 + r15;
            bhi[f].u = Bb[br * 8 + ((2 * s) ^ (br & 7))];
            blo[f].u = Bb[br * 8 + ((2 * s + 1) ^ (br & 7))];
        }
        #pragma unroll
        for (int fi = 0; fi < 4; ++fi)
            #pragma unroll
            for (int fj = 0; fj < 4; ++fj) {
                acc[fi][fj] = __builtin_amdgcn_mfma_f32_16x16x32_bf16(ahi[fi].h, bhi[fj].h, acc[fi][fj], 0, 0, 0);
                acc[fi][fj] = __builtin_amdgcn_mfma_f32_16x16x32_bf16(ahi[fi].h, blo[fj].h, acc[fi][fj], 0, 0, 0);
                acc[fi][fj] = __builtin_amdgcn_mfma_f32_16x16x32_bf16(alo[fi].h, bhi[fj].h, acc[fi][fj], 0, 0, 0);
            }
        __syncthreads();
    }
    int r4 = (lane >> 4) * 4;
    #pragma unroll
    for (int fj = 0; fj < 4; ++fj) {
        int n = n0 + wc * 64 + fj * 16 + r15;
        float bv = BIAS ? bias[n] : 0.f;
        #pragma unroll
        for (int fi = 0; fi < 4; ++fi) {
            int m = m0 + wr * 64 + fi * 16 + r4;
            #pragma unroll
            for (int r = 0; r < 4; ++r)
                C[(size_t)(m + r) * ldc + n] = acc[fi][fj][r] + bv;
        }
    }
}

// ---------------------------------------------------------------------------
// Fused TXL attention (unchanged, fp32).
// ---------------------------------------------------------------------------
__global__ __launch_bounds__(256) void attn_fused(
    const float* __restrict__ qkv, const float* __restrict__ rk,
    const float* __restrict__ u_, const float* __restrict__ v_,
    float* __restrict__ y1)
{
    __shared__ float qu[64][68], qv[64][68], Kt[64][68], Vt[64][68];
    __shared__ float RKs[128][68];
    __shared__ float S[64][68];
    __shared__ float mrow[64], lrow[64], scalef[64];
    __shared__ float pmax[64][16], psum[64][16];

    int tid = threadIdx.x;
    int it = blockIdx.x, b = blockIdx.y, h = blockIdx.z;
    int i0 = it * 64;
    int ti = tid >> 4, tj = tid & 15;

    {
        int r = tid >> 2, c0 = (tid & 3) * 16;
        size_t base = ((size_t)(i0 + r + 512) * 8 + b) * 3072 + h * 64;
        #pragma unroll
        for (int q = 0; q < 4; ++q) {
            int c = c0 + q * 4;
            float4 qq = *(const float4*)&qkv[base + c];
            float4 uu = *(const float4*)&u_[h * 64 + c];
            float4 vv = *(const float4*)&v_[h * 64 + c];
            *(float4*)&qu[r][c] = make_float4(qq.x + uu.x, qq.y + uu.y, qq.z + uu.z, qq.w + uu.w);
            *(float4*)&qv[r][c] = make_float4(qq.x + vv.x, qq.y + vv.y, qq.z + vv.z, qq.w + vv.w);
        }
    }
    if (tid < 64) { mrow[tid] = -1e30f; lrow[tid] = 0.f; }

    float Od[4][4] = {};
    int njt = it + 9;

    for (int jt = 0; jt < njt; ++jt) {
        int j0 = jt * 64;
        __syncthreads();
        {
            int r = tid >> 2, c0 = (tid & 3) * 16;
            size_t kb = ((size_t)(j0 + r) * 8 + b) * 3072 + 1024 + h * 64;
            #pragma unroll
            for (int q = 0; q < 4; ++q) {
                int c = c0 + q * 4;
                *(float4*)&Kt[r][c] = *(const float4*)&qkv[kb + c];
                *(float4*)&Vt[r][c] = *(const float4*)&qkv[kb + 1024 + c];
            }
        }
        {
            int r2 = tid >> 1, c0 = (tid & 1) * 32;
            int jj = j0 - i0 + 448 + r2;
            jj = jj < 0 ? 0 : (jj > 1023 ? 1023 : jj);
            size_t rb = (size_t)jj * 1024 + h * 64;
            #pragma unroll
            for (int q = 0; q < 8; ++q) {
                int c = c0 + q * 4;
                *(float4*)&RKs[r2][c] = *(const float4*)&rk[rb + c];
            }
        }
        __syncthreads();

        float acc[4][4] = {};
        int jlb = (tj - ti) * 4 + 60;
        #pragma unroll 4
        for (int d4 = 0; d4 < 64; d4 += 4) {
            float4 Aq[4], Cq[4], Kv[4], Rv[7];
            #pragma unroll
            for (int i = 0; i < 4; ++i) {
                Aq[i] = *(float4*)&qu[ti * 4 + i][d4];
                Cq[i] = *(float4*)&qv[ti * 4 + i][d4];
                Kv[i] = *(float4*)&Kt[tj * 4 + i][d4];
            }
            #pragma unroll
            for (int t = 0; t < 7; ++t)
                Rv[t] = *(float4*)&RKs[jlb + t][d4];
            #pragma unroll
            for (int i = 0; i < 4; ++i)
                #pragma unroll
                for (int j = 0; j < 4; ++j) {
                    float4 kk = Kv[j];
                    float4 rr = Rv[j - i + 3];
                    acc[i][j] += Aq[i].x * kk.x + Aq[i].y * kk.y + Aq[i].z * kk.z + Aq[i].w * kk.w
                               + Cq[i].x * rr.x + Cq[i].y * rr.y + Cq[i].z * rr.z + Cq[i].w * rr.w;
                }
        }
        #pragma unroll
        for (int i = 0; i < 4; ++i) {
            int gi = i0 + ti * 4 + i;
            float mx = -1e30f;
            #pragma unroll
            for (int j = 0; j < 4; ++j) {
                int gj = j0 + tj * 4 + j;
                float vS = acc[i][j] * 0.125f;
                if (gj > gi + 512) vS = -1e30f;
                acc[i][j] = vS;
                mx = fmaxf(mx, vS);
            }
            pmax[ti * 4 + i][tj] = mx;
        }
        __syncthreads();
        if (tid < 64) {
            float mo = mrow[tid], mn = mo;
            #pragma unroll
            for (int t = 0; t < 16; ++t) mn = fmaxf(mn, pmax[tid][t]);
            mrow[tid] = mn;
            scalef[tid] = __expf(mo - mn);
        }
        __syncthreads();
        #pragma unroll
        for (int i = 0; i < 4; ++i) {
            int ri = ti * 4 + i;
            float mn = mrow[ri];
            float4 pv;
            pv.x = __expf(acc[i][0] - mn);
            pv.y = __expf(acc[i][1] - mn);
            pv.z = __expf(acc[i][2] - mn);
            pv.w = __expf(acc[i][3] - mn);
            *(float4*)&S[ri][tj * 4] = pv;
            psum[ri][tj] = pv.x + pv.y + pv.z + pv.w;
            float scl = scalef[ri];
            #pragma unroll
            for (int j2 = 0; j2 < 4; ++j2) Od[i][j2] *= scl;
        }
        __syncthreads();
        if (tid < 64) {
            float s = 0.f;
            #pragma unroll
            for (int t = 0; t < 16; ++t) s += psum[tid][t];
            lrow[tid] = lrow[tid] * scalef[tid] + s;
        }
        #pragma unroll 4
        for (int jb = 0; jb < 64; jb += 4) {
            float4 p0 = *(float4*)&S[ti * 4 + 0][jb];
            float4 p1 = *(float4*)&S[ti * 4 + 1][jb];
            float4 p2 = *(float4*)&S[ti * 4 + 2][jb];
            float4 p3 = *(float4*)&S[ti * 4 + 3][jb];
            float4 v0 = *(float4*)&Vt[jb + 0][tj * 4];
            float4 v1 = *(float4*)&Vt[jb + 1][tj * 4];
            float4 v2 = *(float4*)&Vt[jb + 2][tj * 4];
            float4 v3 = *(float4*)&Vt[jb + 3][tj * 4];
            float4 pr[4] = {p0, p1, p2, p3};
            #pragma unroll
            for (int i = 0; i < 4; ++i) {
                Od[i][0] += pr[i].x * v0.x + pr[i].y * v1.x + pr[i].z * v2.x + pr[i].w * v3.x;
                Od[i][1] += pr[i].x * v0.y + pr[i].y * v1.y + pr[i].z * v2.y + pr[i].w * v3.y;
                Od[i][2] += pr[i].x * v0.z + pr[i].y * v1.z + pr[i].z * v2.z + pr[i].w * v3.z;
                Od[i][3] += pr[i].x * v0.w + pr[i].y * v1.w + pr[i].z * v2.w + pr[i].w * v3.w;
            }
        }
    }
    __syncthreads();
    #pragma unroll
    for (int i = 0; i < 4; ++i) {
        int ri = ti * 4 + i;
        float inv = 1.f / lrow[ri];
        float4 o = make_float4(Od[i][0] * inv, Od[i][1] * inv, Od[i][2] * inv, Od[i][3] * inv);
        *(float4*)&y1[((size_t)(i0 + ri) * 8 + b) * 1024 + h * 64 + tj * 4] = o;
    }
}

// ---------------------------------------------------------------------------
// Whh -> MFMA A-fragments, per-block contiguous (unchanged layout):
// uint4 offset = g64*12288 + kt*384 + gate*128 + plane*64 + lane.
// ---------------------------------------------------------------------------
__global__ __launch_bounds__(256) void prep_whh(
    const float* __restrict__ Whh, uint4* __restrict__ outp)
{
    int idx = blockIdx.x * 256 + threadIdx.x;
    if (idx >= 393216) return;
    int lane = idx & 63;
    int rest = idx >> 6;
    int gate = rest % 3;
    int kt   = (rest / 3) & 31;
    int g64  = rest / 96;
    int n = gate * 1024 + g64 * 16 + (lane & 15);
    int k = kt * 32 + (lane >> 4) * 8;
    const float* src = Whh + (size_t)n * 1024 + k;
    float4 x0 = *(const float4*)src, x1 = *(const float4*)(src + 4);
    unsigned h[4], l[4];
    split2(x0.x, x0.y, h[0], l[0]);
    split2(x0.z, x0.w, h[1], l[1]);
    split2(x1.x, x1.y, h[2], l[2]);
    split2(x1.z, x1.w, h[3], l[3]);
    outp[((size_t)rest * 2 + 0) * 64 + lane] = make_uint4(h[0], h[1], h[2], h[3]);
    outp[((size_t)rest * 2 + 1) * 64 + lane] = make_uint4(l[0], l[1], l[2], l[3]);
}

// ---------------------------------------------------------------------------
// PERSISTENT GRU v4: TAGGED-DATA DATAFLOW, no flags, no cross-step barrier.
// Each h scalar is an 8B word {tag=step (hi32), f32 bits (lo32)} in ping-pong
// tagged buffers. Consumers spin directly on the words they need (tag==t ->
// payload valid, single hop). Producers just store tagged words; the 2-deep
// pipeline invariant (producing t+1 requires consuming t) makes buffer reuse
// safe. Buffers zeroed per launch (replay-safe).
// ---------------------------------------------------------------------------
__global__ __launch_bounds__(256, 1) void gru_persist4(
    const float* __restrict__ h0,
    unsigned long long* __restrict__ tb0, unsigned long long* __restrict__ tb1,
    const uint4* __restrict__ WhhG, const float* __restrict__ bhh,
    const float* __restrict__ xg, float* __restrict__ out)
{
    __shared__ uint4 Bf[4096];        // h frags: [kt32][plane2][lane64] 64KB
    __shared__ float red[3][64][4];
    int tid = threadIdx.x;
    int lane = tid & 63, wv = tid >> 6;
    int g64 = blockIdx.x;

    int col = lane & 15;
    int d0 = g64 * 16 + (lane >> 4) * 4;
    bool act = (wv == 0) && (col < 8);
    float4 br4 = make_float4(0, 0, 0, 0), bz4 = br4, bn4 = br4, hprev4 = br4;
    if (act) {
        br4 = *(const float4*)&bhh[d0];
        bz4 = *(const float4*)&bhh[1024 + d0];
        bn4 = *(const float4*)&bhh[2048 + d0];
        hprev4 = *(const float4*)&h0[col * 1024 + d0];
    }
    const uint4* wb = WhhG + (size_t)g64 * 12288 + (wv < 3 ? wv : 0) * 128 + lane;

    // task precompute: s = i*256 + tid -> (b, oct, kt)
    int toff[4], tkt[4], tln[4];
    #pragma unroll
    for (int i = 0; i < 4; ++i) {
        int s = i * 256 + tid;
        int b = s & 7, oct = (s >> 3) & 3, kt = s >> 5;
        toff[i] = b * 1024 + kt * 32 + oct * 8;
        tkt[i] = kt;
        tln[i] = oct * 16 + b;
    }

    for (int t = 0; t < 512; ++t) {
        // xg prefetch (independent of h)
        float4 xr4, xz4, xn4;
        if (act) {
            size_t xb = ((size_t)t * 8 + col) * 3072 + d0;
            xr4 = *(const float4*)&xg[xb];
            xz4 = *(const float4*)&xg[xb + 1024];
            xn4 = *(const float4*)&xg[xb + 2048];
        }
        // W chunk 0 prefetch (independent of h)
        uint4 wA[16], wB[16];
        if (wv < 3) {
            #pragma unroll
            for (int q = 0; q < 8; ++q) {
                wA[2 * q]     = wb[q * 384];
                wA[2 * q + 1] = wb[q * 384 + 64];
            }
        }

        // ---- gather h(t) and build Bf
        if (t == 0) {
            #pragma unroll
            for (int i = 0; i < 4; ++i) {
                const float* hp = h0 + toff[i];
                float4 x0 = *(const float4*)hp, x1 = *(const float4*)(hp + 4);
                unsigned hh[4], ll[4];
                split2(x0.x, x0.y, hh[0], ll[0]);
                split2(x0.z, x0.w, hh[1], ll[1]);
                split2(x1.x, x1.y, hh[2], ll[2]);
                split2(x1.z, x1.w, hh[3], ll[3]);
                Bf[(tkt[i] * 2 + 0) * 64 + tln[i]] = make_uint4(hh[0], hh[1], hh[2], hh[3]);
                Bf[(tkt[i] * 2 + 1) * 64 + tln[i]] = make_uint4(ll[0], ll[1], ll[2], ll[3]);
            }
        } else {
            const unsigned long long* tb = (t & 1) ? tb1 : tb0;
            unsigned tg = (unsigned)t;
            #pragma unroll
            for (int g = 0; g < 2; ++g) {
                unsigned long long v[16];
                for (;;) {
                    #pragma unroll
                    for (int j = 0; j < 16; ++j)
                        v[j] = ld_coh64(tb + toff[g * 2 + (j >> 3)] + (j & 7));
                    bool ok = true;
                    #pragma unroll
                    for (int j = 0; j < 16; ++j)
                        ok = ok && ((unsigned)(v[j] >> 32) == tg);
                    if (ok) break;
                }
                #pragma unroll
                for (int i2 = 0; i2 < 2; ++i2) {
                    int i = g * 2 + i2;
                    float x[8];
                    #pragma unroll
                    for (int q = 0; q < 8; ++q)
                        x[q] = __uint_as_float((unsigned)(v[i2 * 8 + q] & 0xffffffffu));
                    unsigned hh[4], ll[4];
                    split2(x[0], x[1], hh[0], ll[0]);
                    split2(x[2], x[3], hh[1], ll[1]);
                    split2(x[4], x[5], hh[2], ll[2]);
                    split2(x[6], x[7], hh[3], ll[3]);
                    Bf[(tkt[i] * 2 + 0) * 64 + tln[i]] = make_uint4(hh[0], hh[1], hh[2], hh[3]);
                    Bf[(tkt[i] * 2 + 1) * 64 + tln[i]] = make_uint4(ll[0], ll[1], ll[2], ll[3]);
                }
            }
        }
        __syncthreads();

        // ---- MFMA: 4 chunks of 8 kt, 4 accumulators, reg dbuf for W
        #define GRU_LOAD(dst, c0)                                   \
            _Pragma("unroll")                                       \
            for (int q = 0; q < 8; ++q) {                           \
                dst[2 * q]     = wb[((c0) * 8 + q) * 384];          \
                dst[2 * q + 1] = wb[((c0) * 8 + q) * 384 + 64];     \
            }
        #define GRU_COMP(src, c0, a)                                \
            _Pragma("unroll")                                       \
            for (int q = 0; q < 8; ++q) {                           \
                int kt = (c0) * 8 + q;                              \
                FragU ah, al, bh, bl;                               \
                ah.u = src[2 * q]; al.u = src[2 * q + 1];           \
                bh.u = Bf[(kt * 2 + 0) * 64 + lane];                \
                bl.u = Bf[(kt * 2 + 1) * 64 + lane];                \
                a = __builtin_amdgcn_mfma_f32_16x16x32_bf16(ah.h, bh.h, a, 0, 0, 0); \
                a = __builtin_amdgcn_mfma_f32_16x16x32_bf16(ah.h, bl.h, a, 0, 0, 0); \
                a = __builtin_amdgcn_mfma_f32_16x16x32_bf16(al.h, bh.h, a, 0, 0, 0); \
            }
        if (wv < 3) {
            f32x4 a0 = 0.0f, a1 = 0.0f, a2 = 0.0f, a3 = 0.0f;
            GRU_LOAD(wB, 1);
            GRU_COMP(wA, 0, a0);
            GRU_LOAD(wA, 2);
            GRU_COMP(wB, 1, a1);
            GRU_LOAD(wB, 3);
            GRU_COMP(wA, 2, a2);
            GRU_COMP(wB, 3, a3);
            f32x4 av = (a0 + a1) + (a2 + a3);
            *(f32x4*)&red[wv][lane][0] = av;
        }
        #undef GRU_LOAD
        #undef GRU_COMP
        __syncthreads();

        // ---- producer epilogue: tagged stores (self-validating), no barrier
        if (act) {
            f32x4 aR = *(f32x4*)&red[0][lane][0];
            f32x4 aZ = *(f32x4*)&red[1][lane][0];
            f32x4 aN = *(f32x4*)&red[2][lane][0];
            float xr[4] = {xr4.x, xr4.y, xr4.z, xr4.w};
            float xz[4] = {xz4.x, xz4.y, xz4.z, xz4.w};
            float xn[4] = {xn4.x, xn4.y, xn4.z, xn4.w};
            float hp[4] = {hprev4.x, hprev4.y, hprev4.z, hprev4.w};
            float br[4] = {br4.x, br4.y, br4.z, br4.w};
            float bz[4] = {bz4.x, bz4.y, bz4.z, bz4.w};
            float bn[4] = {bn4.x, bn4.y, bn4.z, bn4.w};
            float hn[4];
            #pragma unroll
            for (int r = 0; r < 4; ++r) {
                float rr = 1.f / (1.f + __expf(-(xr[r] + aR[r] + br[r])));
                float zz = 1.f / (1.f + __expf(-(xz[r] + aZ[r] + bz[r])));
                float nn = tanhf(xn[r] + rr * (aN[r] + bn[r]));
                hn[r] = (1.f - zz) * nn + zz * hp[r];
            }
            unsigned long long* tbn = ((t + 1) & 1) ? tb1 : tb0;
            unsigned long long tagw = ((unsigned long long)(unsigned)(t + 1)) << 32;
            int base = col * 1024 + d0;
            st_coh64(tbn + base + 0, tagw | (unsigned long long)__float_as_uint(hn[0]));
            st_coh64(tbn + base + 1, tagw | (unsigned long long)__float_as_uint(hn[1]));
            st_coh64(tbn + base + 2, tagw | (unsigned long long)__float_as_uint(hn[2]));
            st_coh64(tbn + base + 3, tagw | (unsigned long long)__float_as_uint(hn[3]));
            *(float4*)&out[((size_t)t * 8 + col) * 1024 + d0] =
                make_float4(hn[0], hn[1], hn[2], hn[3]);
            hprev4 = make_float4(hn[0], hn[1], hn[2], hn[3]);
        }
    }
}

// ---------------------------------------------------------------------------
// Fallback: one GRU step via MFMA (r7 kernel, unchanged).
// ---------------------------------------------------------------------------
__global__ __launch_bounds__(192, 1) void gru_step_mfma(
    const float* __restrict__ hin, float* __restrict__ hout,
    const uint4* __restrict__ WhhG, const float* __restrict__ bhh,
    const float* __restrict__ xg, float* __restrict__ out, int t)
{
    __shared__ uint4 Bf[4096];
    __shared__ float red[3][64][4];
    int tid = threadIdx.x;
    int lane = tid & 63, wv = tid >> 6;
    int g64 = blockIdx.x;

    int col = lane & 15;
    int d0 = g64 * 16 + (lane >> 4) * 4;
    bool act = (wv == 0) && (col < 8);
    float4 xr4, xz4, xn4, hp4, br4, bz4, bn4;
    if (act) {
        size_t xb = ((size_t)t * 8 + col) * 3072 + d0;
        xr4 = *(const float4*)&xg[xb];
        xz4 = *(const float4*)&xg[xb + 1024];
        xn4 = *(const float4*)&xg[xb + 2048];
        hp4 = *(const float4*)&hin[col * 1024 + d0];
        br4 = *(const float4*)&bhh[d0];
        bz4 = *(const float4*)&bhh[1024 + d0];
        bn4 = *(const float4*)&bhh[2048 + d0];
    }

    const uint4* wb = WhhG + (size_t)g64 * 12288 + wv * 128 + lane;
    uint4 wA[16], wB[16];
    #pragma unroll
    for (int q = 0; q < 8; ++q) {
        wA[2 * q]     = wb[q * 384];
        wA[2 * q + 1] = wb[q * 384 + 64];
    }

    for (int s = tid; s < 1024; s += 192) {
        int b = s & 7, oct = (s >> 3) & 3, kt = s >> 5;
        const float* hp = hin + b * 1024 + kt * 32 + oct * 8;
        float4 x0 = *(const float4*)hp, x1 = *(const float4*)(hp + 4);
        unsigned hh[4], ll[4];
        split2(x0.x, x0.y, hh[0], ll[0]);
        split2(x0.z, x0.w, hh[1], ll[1]);
        split2(x1.x, x1.y, hh[2], ll[2]);
        split2(x1.z, x1.w, hh[3], ll[3]);
        int ln = oct * 16 + b;
        Bf[(kt * 2 + 0) * 64 + ln] = make_uint4(hh[0], hh[1], hh[2], hh[3]);
        Bf[(kt * 2 + 1) * 64 + ln] = make_uint4(ll[0], ll[1], ll[2], ll[3]);
    }
    __syncthreads();

    f32x4 acc = 0.0f;
    #define GRU_LOAD(dst, c0)                                   \
        _Pragma("unroll")                                       \
        for (int q = 0; q < 8; ++q) {                           \
            dst[2 * q]     = wb[((c0) * 8 + q) * 384];          \
            dst[2 * q + 1] = wb[((c0) * 8 + q) * 384 + 64];     \
        }
    #define GRU_COMP(src, c0)                                   \
        _Pragma("unroll")                                       \
        for (int q = 0; q < 8; ++q) {                           \
            int kt = (c0) * 8 + q;                              \
            FragU ah, al, bh, bl;                               \
            ah.u = src[2 * q]; al.u = src[2 * q + 1];           \
            bh.u = Bf[(kt * 2 + 0) * 64 + lane];                \
            bl.u = Bf[(kt * 2 + 1) * 64 + lane];                \
            acc = __builtin_amdgcn_mfma_f32_16x16x32_bf16(ah.h, bh.h, acc, 0, 0, 0); \
            acc = __builtin_amdgcn_mfma_f32_16x16x32_bf16(ah.h, bl.h, acc, 0, 0, 0); \
            acc = __builtin_amdgcn_mfma_f32_16x16x32_bf16(al.h, bh.h, acc, 0, 0, 0); \
        }
    GRU_LOAD(wB, 1);
    GRU_COMP(wA, 0);
    GRU_LOAD(wA, 2);
    GRU_COMP(wB, 1);
    GRU_LOAD(wB, 3);
    GRU_COMP(wA, 2);
    GRU_COMP(wB, 3);
    #undef GRU_LOAD
    #undef GRU_COMP

    *(f32x4*)&red[wv][lane][0] = acc;
    __syncthreads();

    if (act) {
        f32x4 aR = *(f32x4*)&red[0][lane][0];
        f32x4 aZ = *(f32x4*)&red[1][lane][0];
        f32x4 aN = *(f32x4*)&red[2][lane][0];
        float xr[4] = {xr4.x, xr4.y, xr4.z, xr4.w};
        float xz[4] = {xz4.x, xz4.y, xz4.z, xz4.w};
        float xn[4] = {xn4.x, xn4.y, xn4.z, xn4.w};
        float hp[4] = {hp4.x, hp4.y, hp4.z, hp4.w};
        float br[4] = {br4.x, br4.y, br4.z, br4.w};
        float bz[4] = {bz4.x, bz4.y, bz4.z, bz4.w};
        float bn[4] = {bn4.x, bn4.y, bn4.z, bn4.w};
        float hn[4];
        #pragma unroll
        for (int r = 0; r < 4; ++r) {
            float rr = 1.f / (1.f + __expf(-(xr[r] + aR[r] + br[r])));
            float zz = 1.f / (1.f + __expf(-(xz[r] + aZ[r] + bz[r])));
            float nn = tanhf(xn[r] + rr * (aN[r] + bn[r]));
            hn[r] = (1.f - zz) * nn + zz * hp[r];
        }
        float4 hv = make_float4(hn[0], hn[1], hn[2], hn[3]);
        *(float4*)&hout[col * 1024 + d0] = hv;
        *(float4*)&out[((size_t)t * 8 + col) * 1024 + d0] = hv;
    }
}

// ---------------------------------------------------------------------------
extern "C" void kernel_launch(void* const* d_in, const int* in_sizes, int n_in,
                              void* d_out, int out_size, void* d_ws, size_t ws_size,
                              hipStream_t stream) {
    (void)in_sizes; (void)n_in; (void)out_size; (void)ws_size;
    const float* inputs = (const float*)d_in[0];
    const float* r_in   = (const float*)d_in[1];
    const float* u_in   = (const float*)d_in[2];
    const float* v_in   = (const float*)d_in[3];
    const float* mem    = (const float*)d_in[4];
    const float* Wqkv   = (const float*)d_in[5];
    const float* Wr     = (const float*)d_in[6];
    const float* Wo     = (const float*)d_in[7];
    const float* Wih    = (const float*)d_in[8];
    const float* Whh    = (const float*)d_in[9];
    const float* bih    = (const float*)d_in[10];
    const float* bhh    = (const float*)d_in[11];
    const float* h0     = (const float*)d_in[12];
    float* out = (float*)d_out;
    float* ws = (float*)d_ws;

    float*    qkv   = ws;                       // dead after attn; reused for WhhG
    float*    rk    = ws + 25165824;
    float*    y1    = ws + 26214400;
    float*    y2    = ws + 30408704;
    float*    xg    = ws + 34603008;
    float*    hA    = ws + 47185920;
    float*    hB    = ws + 47194112;
    unsigned* WqkvP = (unsigned*)(ws + 47202304);
    unsigned* WrP   = (unsigned*)(ws + 50348032);
    unsigned* WoP   = (unsigned*)(ws + 51396608);
    unsigned* WihP  = (unsigned*)(ws + 52445184);
    unsigned long long* tb0 = (unsigned long long*)(ws + 55590912);  // 8192 x 8B
    unsigned long long* tb1 = (unsigned long long*)(ws + 55607296);  // 8192 x 8B
    uint4*    WhhG  = (uint4*)qkv;

    dim3 blk(256);
    // ---- weight prep (GEMM layouts)
    prep_w<true ><<<1536, blk, 0, stream>>>(Wqkv, WqkvP, 3072, 1024, 3072);
    prep_w<true ><<< 512, blk, 0, stream>>>(Wr,   WrP,   1024, 1024, 1024);
    prep_w<true ><<< 512, blk, 0, stream>>>(Wo,   WoP,   1024, 1024, 1024);
    prep_w<false><<<1536, blk, 0, stream>>>(Wih,  WihP,  3072, 1024, 1024);
    hipMemsetAsync(tb0, 0, 131072, stream);   // zero BOTH tagged buffers (replay-safe)

    // ---- qkv = [mem; inputs] @ W_qkv   (8192 x 3072, K=1024)
    gemm_mfma<1, false><<<dim3(24, 64), blk, 0, stream>>>(
        mem, inputs, WqkvP, nullptr, qkv, 8192, 3072, 1024, 1024, 3072);
    // ---- rk = r @ W_r                  (1024 x 1024)
    gemm_mfma<0, false><<<dim3(8, 8), blk, 0, stream>>>(
        r_in, nullptr, WrP, nullptr, rk, 1024, 1024, 1024, 1024, 1024);
    // ---- fused attention -> y1
    attn_fused<<<dim3(8, 8, 16), blk, 0, stream>>>(qkv, rk, u_in, v_in, y1);
    // ---- Whh fragment prep (into dead qkv space; after attn in-stream)
    prep_whh<<<1536, blk, 0, stream>>>(Whh, WhhG);
    // ---- y2 = y1 @ W_o                 (4096 x 1024)
    gemm_mfma<0, false><<<dim3(8, 32), blk, 0, stream>>>(
        y1, nullptr, WoP, nullptr, y2, 4096, 1024, 1024, 1024, 1024);
    // ---- xg = y2 @ W_ih^T + b_ih       (4096 x 3072)
    gemm_mfma<0, true><<<dim3(24, 32), blk, 0, stream>>>(
        y2, nullptr, WihP, bih, xg, 4096, 3072, 1024, 1024, 3072);

    // ---- GRU recurrence: persistent v4 (tagged dataflow); fallback loop
    {
        const float* a0 = h0;
        unsigned long long* a1 = tb0; unsigned long long* a2 = tb1;
        const uint4* a3 = WhhG; const float* a4 = bhh; const float* a5 = xg;
        float* a6 = out;
        void* args[7] = {&a0, &a1, &a2, &a3, &a4, &a5, &a6};
        hipError_t e = hipLaunchCooperativeKernel((void*)gru_persist4,
                                                  dim3(64), dim3(256), args, 0, stream);
        if (e != hipSuccess) {
            const float* hin = h0;
            for (int s = 0; s < 512; ++s) {
                float* hp = (s & 1) ? hB : hA;
                gru_step_mfma<<<64, dim3(192), 0, stream>>>(hin, hp, WhhG, bhh, xg, out, s);
                hin = hp;
            }
        }
    }
}

// Round 11
// 4719.106 us; speedup vs baseline: 1.4406x; 1.4406x over previous
//
#include <hip/hip_runtime.h>
#include <math.h>

// D_MODEL=1024, N_HEADS=16, D_HEAD=64, QLEN=512, MLEN=512, KLEN=1024, BATCH=8

typedef short bf16x8 __attribute__((ext_vector_type(8)));
typedef float f32x4 __attribute__((ext_vector_type(4)));

union FragU { uint4 u; bf16x8 h; };

// split two fp32 into packed bf16-hi (truncated) and bf16-lo (exact residual, truncated)
__device__ inline void split2(float x0, float x1, unsigned& hi, unsigned& lo) {
    unsigned u0 = __float_as_uint(x0), u1 = __float_as_uint(x1);
    float h0 = __uint_as_float(u0 & 0xffff0000u);
    float h1 = __uint_as_float(u1 & 0xffff0000u);
    unsigned l0 = __float_as_uint(x0 - h0), l1 = __float_as_uint(x1 - h1);
    hi = (u0 >> 16) | (u1 & 0xffff0000u);
    lo = (l0 >> 16) | (l1 & 0xffff0000u);
}

// coherent (agent-scope, cache-bypassing) 8B load/store of h state
__device__ __forceinline__ unsigned long long ld_coh64(const void* p) {
    return __hip_atomic_load((const unsigned long long*)p, __ATOMIC_RELAXED,
                             __HIP_MEMORY_SCOPE_AGENT);
}
__device__ __forceinline__ void st_coh64(void* p, unsigned long long v) {
    __hip_atomic_store((unsigned long long*)p, v, __ATOMIC_RELAXED,
                       __HIP_MEMORY_SCOPE_AGENT);
}

// async 16B global -> LDS (lds dst wave-uniform base; HW adds lane*16)
__device__ __forceinline__ void gl_lds16(const uint4* g, uint4* l) {
    __builtin_amdgcn_global_load_lds(
        (const __attribute__((address_space(1))) uint4*)g,
        (__attribute__((address_space(3))) uint4*)l, 16, 0, 0);
}

// ---------------------------------------------------------------------------
// Weight/activation prep: X (fp32, [n][k] if !TR else [k][n]) -> u32[n][K],
// 32-k tile = 8 16B slots {hi,lo,...} XOR-swizzled by (n&7).
// ---------------------------------------------------------------------------
template<bool TR>
__global__ __launch_bounds__(256) void prep_w(
    const float* __restrict__ W, unsigned* __restrict__ out, int Nr, int K, int ldw)
{
    int idx = blockIdx.x * 256 + threadIdx.x;
    int cpr = K >> 3;
    if (idx >= Nr * cpr) return;
    int n, c;
    if (TR) { n = idx % Nr; c = idx / Nr; }
    else    { c = idx % cpr; n = idx / cpr; }
    int kt = c >> 2, j = c & 3;
    int k = kt * 32 + j * 8;
    float x[8];
    #pragma unroll
    for (int i = 0; i < 8; ++i)
        x[i] = TR ? W[(size_t)(k + i) * ldw + n] : W[(size_t)n * ldw + k + i];
    unsigned h[4], l[4];
    split2(x[0], x[1], h[0], l[0]);
    split2(x[2], x[3], h[1], l[1]);
    split2(x[4], x[5], h[2], l[2]);
    split2(x[6], x[7], h[3], l[3]);
    unsigned* base = out + (size_t)n * K + kt * 32;
    *(uint4*)(base + (((2 * j) ^ (n & 7)) * 4))     = make_uint4(h[0], h[1], h[2], h[3]);
    *(uint4*)(base + (((2 * j + 1) ^ (n & 7)) * 4)) = make_uint4(l[0], l[1], l[2], l[3]);
}

// ---------------------------------------------------------------------------
// cat = [mem; inputs] -> pre-split swizzled u32[8192][1024].
// ---------------------------------------------------------------------------
__global__ __launch_bounds__(256) void prep_cat(
    const float* __restrict__ mem, const float* __restrict__ inputs,
    unsigned* __restrict__ out)
{
    int idx = blockIdx.x * 256 + threadIdx.x;
    if (idx >= 1048576) return;
    int c = idx & 127, n = idx >> 7;
    int kt = c >> 2, j = c & 3;
    int k = kt * 32 + j * 8;
    const float* src = (n < 4096) ? (mem + (size_t)n * 1024 + k)
                                  : (inputs + (size_t)(n - 4096) * 1024 + k);
    float4 x0 = *(const float4*)src, x1 = *(const float4*)(src + 4);
    unsigned h[4], l[4];
    split2(x0.x, x0.y, h[0], l[0]);
    split2(x0.z, x0.w, h[1], l[1]);
    split2(x1.x, x1.y, h[2], l[2]);
    split2(x1.z, x1.w, h[3], l[3]);
    unsigned* base = out + (size_t)n * 1024 + kt * 32;
    *(uint4*)(base + (((2 * j) ^ (n & 7)) * 4))     = make_uint4(h[0], h[1], h[2], h[3]);
    *(uint4*)(base + (((2 * j + 1) ^ (n & 7)) * 4)) = make_uint4(l[0], l[1], l[2], l[3]);
}

// ---------------------------------------------------------------------------
// Split-bf16 MFMA GEMM, BOTH operands pre-split swizzled u32[rows][K],
// staged via global_load_lds width=16 (m97 pattern). 128x128 tile, BK=32,
// 256 threads (2x2 waves of 64x64), identical frag reads/MFMA/epilogue to
// the verified gemm_mfma.
// ---------------------------------------------------------------------------
template<bool BIAS>
__global__ __launch_bounds__(256) void gemm_pp(
    const uint4* __restrict__ Ap4, const uint4* __restrict__ Bp4,
    const float* __restrict__ bias, float* __restrict__ C, int K, int ldc)
{
    __shared__ uint4 Ab[1024];
    __shared__ uint4 Bb[1024];
    int tid = threadIdx.x;
    int lane = tid & 63, wid = tid >> 6;
    int wr = wid >> 1, wc = wid & 1;
    int n0 = blockIdx.x * 128, m0 = blockIdx.y * 128;
    int r15 = lane & 15, s = lane >> 4;
    int K4 = K >> 2;                     // row stride in uint4

    f32x4 acc[4][4];
    #pragma unroll
    for (int i = 0; i < 4; ++i)
        #pragma unroll
        for (int j = 0; j < 4; ++j) acc[i][j] = 0.0f;

    for (int kt = 0; kt < (K >> 5); ++kt) {
        #pragma unroll
        for (int q = 0; q < 4; ++q) {
            int base = q * 256 + wid * 64;      // wave-uniform LDS base
            int idx  = base + lane;             // per-lane element
            int row = idx >> 3, slot = idx & 7;
            gl_lds16(Ap4 + (size_t)(m0 + row) * K4 + kt * 8 + slot, &Ab[base]);
            gl_lds16(Bp4 + (size_t)(n0 + row) * K4 + kt * 8 + slot, &Bb[base]);
        }
        __syncthreads();   // vmcnt(0) drain: tiles landed
        FragU ahi[4], alo[4], bhi[4], blo[4];
        #pragma unroll
        for (int f = 0; f < 4; ++f) {
            int ar = wr * 64 + f * 16 + r15;
            ahi[f].u = Ab[ar * 8 + ((2 * s) ^ (ar & 7))];
            alo[f].u = Ab[ar * 8 + ((2 * s + 1) ^ (ar & 7))];
            int br = wc * 64 + f * 16 + r15;
            bhi[f].u = Bb[br * 8 + ((2 * s) ^ (br & 7))];
            blo[f].u = Bb[br * 8 + ((2 * s + 1) ^ (br & 7))];
        }
        #pragma unroll
        for (int fi = 0; fi < 4; ++fi)
            #pragma unroll
            for (int fj = 0; fj < 4; ++fj) {
                acc[fi][fj] = __builtin_amdgcn_mfma_f32_16x16x32_bf16(ahi[fi].h, bhi[fj].h, acc[fi][fj], 0, 0, 0);
                acc[fi][fj] = __builtin_amdgcn_mfma_f32_16x16x32_bf16(ahi[fi].h, blo[fj].h, acc[fi][fj], 0, 0, 0);
                acc[fi][fj] = __builtin_amdgcn_mfma_f32_16x16x32_bf16(alo[fi].h, bhi[fj].h, acc[fi][fj], 0, 0, 0);
            }
        __syncthreads();
    }
    int r4 = (lane >> 4) * 4;
    #pragma unroll
    for (int fj = 0; fj < 4; ++fj) {
        int n = n0 + wc * 64 + fj * 16 + r15;
        float bv = BIAS ? bias[n] : 0.f;
        #pragma unroll
        for (int fi = 0; fi < 4; ++fi) {
            int m = m0 + wr * 64 + fi * 16 + r4;
            #pragma unroll
            for (int r = 0; r < 4; ++r)
                C[(size_t)(m + r) * ldc + n] = acc[fi][fj][r] + bv;
        }
    }
}

// ---------------------------------------------------------------------------
// Original split-bf16 GEMM (in-kernel A conversion) — kept for the tiny rk.
// ---------------------------------------------------------------------------
template<int AMODE, bool BIAS>
__global__ __launch_bounds__(256) void gemm_mfma(
    const float* __restrict__ A, const float* __restrict__ A2,
    const unsigned* __restrict__ Bp, const float* __restrict__ bias,
    float* __restrict__ C, int M, int N, int K, int lda, int ldc)
{
    __shared__ uint4 Ab[1024];
    __shared__ uint4 Bb[1024];
    int tid = threadIdx.x;
    int lane = tid & 63, wid = tid >> 6;
    int wr = wid >> 1, wc = wid & 1;
    int n0 = blockIdx.x * 128, m0 = blockIdx.y * 128;
    int r15 = lane & 15, s = lane >> 4;

    f32x4 acc[4][4];
    #pragma unroll
    for (int i = 0; i < 4; ++i)
        #pragma unroll
        for (int j = 0; j < 4; ++j) acc[i][j] = 0.0f;

    for (int kt = 0; kt < (K >> 5); ++kt) {
        int k0 = kt * 32;
        #pragma unroll
        for (int q = 0; q < 2; ++q) {
            int idx = q * 256 + tid;
            int row = idx >> 2, j = idx & 3;
            const float* ap;
            if (AMODE == 1) {
                int gm = m0 + row;
                ap = (gm < 4096) ? (A + (size_t)gm * lda) : (A2 + (size_t)(gm - 4096) * lda);
            } else {
                ap = A + (size_t)(m0 + row) * lda;
            }
            float4 x0 = *(const float4*)(ap + k0 + j * 8);
            float4 x1 = *(const float4*)(ap + k0 + j * 8 + 4);
            unsigned h[4], l[4];
            split2(x0.x, x0.y, h[0], l[0]);
            split2(x0.z, x0.w, h[1], l[1]);
            split2(x1.x, x1.y, h[2], l[2]);
            split2(x1.z, x1.w, h[3], l[3]);
            Ab[row * 8 + (((2 * j) ^ (row & 7)))]     = make_uint4(h[0], h[1], h[2], h[3]);
            Ab[row * 8 + (((2 * j + 1) ^ (row & 7)))] = make_uint4(l[0], l[1], l[2], l[3]);
        }
        #pragma unroll
        for (int q = 0; q < 4; ++q) {
            int idx = q * 256 + tid;
            int row = idx >> 3, slot = idx & 7;
            Bb[idx] = *(const uint4*)(Bp + (size_t)(n0 + row) * K + k0 + slot * 4);
        }
        __syncthreads();
        FragU ahi[4], alo[4], bhi[4], blo[4];
        #pragma unroll
        for (int f = 0; f < 4; ++f) {
            int ar = wr * 64 + f * 16 + r15;
            ahi[f].u = Ab[ar * 8 + ((2 * s) ^ (ar & 7))];
            alo[f].u = Ab[ar * 8 + ((2 * s + 1) ^ (ar & 7))];
            int br = wc * 64 + f * 16 + r15;
            bhi[f].u = Bb[br * 8 + ((2 * s) ^ (br & 7))];
            blo[f].u = Bb[br * 8 + ((2 * s + 1) ^ (br & 7))];
        }
        #pragma unroll
        for (int fi = 0; fi < 4; ++fi)
            #pragma unroll
            for (int fj = 0; fj < 4; ++fj) {
                acc[fi][fj] = __builtin_amdgcn_mfma_f32_16x16x32_bf16(ahi[fi].h, bhi[fj].h, acc[fi][fj], 0, 0, 0);
                acc[fi][fj] = __builtin_amdgcn_mfma_f32_16x16x32_bf16(ahi[fi].h, blo[fj].h, acc[fi][fj], 0, 0, 0);
                acc[fi][fj] = __builtin_amdgcn_mfma_f32_16x16x32_bf16(alo[fi].h, bhi[fj].h, acc[fi][fj], 0, 0, 0);
            }
        __syncthreads();
    }
    int r4 = (lane >> 4) * 4;
    #pragma unroll
    for (int fj = 0; fj < 4; ++fj) {
        int n = n0 + wc * 64 + fj * 16 + r15;
        float bv = BIAS ? bias[n] : 0.f;
        #pragma unroll
        for (int fi = 0; fi < 4; ++fi) {
            int m = m0 + wr * 64 + fi * 16 + r4;
            #pragma unroll
            for (int r = 0; r < 4; ++r)
                C[(size_t)(m + r) * ldc + n] = acc[fi][fj][r] + bv;
        }
    }
}

// ---------------------------------------------------------------------------
// Fused TXL attention (unchanged, fp32).
// ---------------------------------------------------------------------------
__global__ __launch_bounds__(256) void attn_fused(
    const float* __restrict__ qkv, const float* __restrict__ rk,
    const float* __restrict__ u_, const float* __restrict__ v_,
    float* __restrict__ y1)
{
    __shared__ float qu[64][68], qv[64][68], Kt[64][68], Vt[64][68];
    __shared__ float RKs[128][68];
    __shared__ float S[64][68];
    __shared__ float mrow[64], lrow[64], scalef[64];
    __shared__ float pmax[64][16], psum[64][16];

    int tid = threadIdx.x;
    int it = blockIdx.x, b = blockIdx.y, h = blockIdx.z;
    int i0 = it * 64;
    int ti = tid >> 4, tj = tid & 15;

    {
        int r = tid >> 2, c0 = (tid & 3) * 16;
        size_t base = ((size_t)(i0 + r + 512) * 8 + b) * 3072 + h * 64;
        #pragma unroll
        for (int q = 0; q < 4; ++q) {
            int c = c0 + q * 4;
            float4 qq = *(const float4*)&qkv[base + c];
            float4 uu = *(const float4*)&u_[h * 64 + c];
            float4 vv = *(const float4*)&v_[h * 64 + c];
            *(float4*)&qu[r][c] = make_float4(qq.x + uu.x, qq.y + uu.y, qq.z + uu.z, qq.w + uu.w);
            *(float4*)&qv[r][c] = make_float4(qq.x + vv.x, qq.y + vv.y, qq.z + vv.z, qq.w + vv.w);
        }
    }
    if (tid < 64) { mrow[tid] = -1e30f; lrow[tid] = 0.f; }

    float Od[4][4] = {};
    int njt = it + 9;

    for (int jt = 0; jt < njt; ++jt) {
        int j0 = jt * 64;
        __syncthreads();
        {
            int r = tid >> 2, c0 = (tid & 3) * 16;
            size_t kb = ((size_t)(j0 + r) * 8 + b) * 3072 + 1024 + h * 64;
            #pragma unroll
            for (int q = 0; q < 4; ++q) {
                int c = c0 + q * 4;
                *(float4*)&Kt[r][c] = *(const float4*)&qkv[kb + c];
                *(float4*)&Vt[r][c] = *(const float4*)&qkv[kb + 1024 + c];
            }
        }
        {
            int r2 = tid >> 1, c0 = (tid & 1) * 32;
            int jj = j0 - i0 + 448 + r2;
            jj = jj < 0 ? 0 : (jj > 1023 ? 1023 : jj);
            size_t rb = (size_t)jj * 1024 + h * 64;
            #pragma unroll
            for (int q = 0; q < 8; ++q) {
                int c = c0 + q * 4;
                *(float4*)&RKs[r2][c] = *(const float4*)&rk[rb + c];
            }
        }
        __syncthreads();

        float acc[4][4] = {};
        int jlb = (tj - ti) * 4 + 60;
        #pragma unroll 4
        for (int d4 = 0; d4 < 64; d4 += 4) {
            float4 Aq[4], Cq[4], Kv[4], Rv[7];
            #pragma unroll
            for (int i = 0; i < 4; ++i) {
                Aq[i] = *(float4*)&qu[ti * 4 + i][d4];
                Cq[i] = *(float4*)&qv[ti * 4 + i][d4];
                Kv[i] = *(float4*)&Kt[tj * 4 + i][d4];
            }
            #pragma unroll
            for (int t = 0; t < 7; ++t)
                Rv[t] = *(float4*)&RKs[jlb + t][d4];
            #pragma unroll
            for (int i = 0; i < 4; ++i)
                #pragma unroll
                for (int j = 0; j < 4; ++j) {
                    float4 kk = Kv[j];
                    float4 rr = Rv[j - i + 3];
                    acc[i][j] += Aq[i].x * kk.x + Aq[i].y * kk.y + Aq[i].z * kk.z + Aq[i].w * kk.w
                               + Cq[i].x * rr.x + Cq[i].y * rr.y + Cq[i].z * rr.z + Cq[i].w * rr.w;
                }
        }
        #pragma unroll
        for (int i = 0; i < 4; ++i) {
            int gi = i0 + ti * 4 + i;
            float mx = -1e30f;
            #pragma unroll
            for (int j = 0; j < 4; ++j) {
                int gj = j0 + tj * 4 + j;
                float vS = acc[i][j] * 0.125f;
                if (gj > gi + 512) vS = -1e30f;
                acc[i][j] = vS;
                mx = fmaxf(mx, vS);
            }
            pmax[ti * 4 + i][tj] = mx;
        }
        __syncthreads();
        if (tid < 64) {
            float mo = mrow[tid], mn = mo;
            #pragma unroll
            for (int t = 0; t < 16; ++t) mn = fmaxf(mn, pmax[tid][t]);
            mrow[tid] = mn;
            scalef[tid] = __expf(mo - mn);
        }
        __syncthreads();
        #pragma unroll
        for (int i = 0; i < 4; ++i) {
            int ri = ti * 4 + i;
            float mn = mrow[ri];
            float4 pv;
            pv.x = __expf(acc[i][0] - mn);
            pv.y = __expf(acc[i][1] - mn);
            pv.z = __expf(acc[i][2] - mn);
            pv.w = __expf(acc[i][3] - mn);
            *(float4*)&S[ri][tj * 4] = pv;
            psum[ri][tj] = pv.x + pv.y + pv.z + pv.w;
            float scl = scalef[ri];
            #pragma unroll
            for (int j2 = 0; j2 < 4; ++j2) Od[i][j2] *= scl;
        }
        __syncthreads();
        if (tid < 64) {
            float s = 0.f;
            #pragma unroll
            for (int t = 0; t < 16; ++t) s += psum[tid][t];
            lrow[tid] = lrow[tid] * scalef[tid] + s;
        }
        #pragma unroll 4
        for (int jb = 0; jb < 64; jb += 4) {
            float4 p0 = *(float4*)&S[ti * 4 + 0][jb];
            float4 p1 = *(float4*)&S[ti * 4 + 1][jb];
            float4 p2 = *(float4*)&S[ti * 4 + 2][jb];
            float4 p3 = *(float4*)&S[ti * 4 + 3][jb];
            float4 v0 = *(float4*)&Vt[jb + 0][tj * 4];
            float4 v1 = *(float4*)&Vt[jb + 1][tj * 4];
            float4 v2 = *(float4*)&Vt[jb + 2][tj * 4];
            float4 v3 = *(float4*)&Vt[jb + 3][tj * 4];
            float4 pr[4] = {p0, p1, p2, p3};
            #pragma unroll
            for (int i = 0; i < 4; ++i) {
                Od[i][0] += pr[i].x * v0.x + pr[i].y * v1.x + pr[i].z * v2.x + pr[i].w * v3.x;
                Od[i][1] += pr[i].x * v0.y + pr[i].y * v1.y + pr[i].z * v2.y + pr[i].w * v3.y;
                Od[i][2] += pr[i].x * v0.z + pr[i].y * v1.z + pr[i].z * v2.z + pr[i].w * v3.z;
                Od[i][3] += pr[i].x * v0.w + pr[i].y * v1.w + pr[i].z * v2.w + pr[i].w * v3.w;
            }
        }
    }
    __syncthreads();
    #pragma unroll
    for (int i = 0; i < 4; ++i) {
        int ri = ti * 4 + i;
        float inv = 1.f / lrow[ri];
        float4 o = make_float4(Od[i][0] * inv, Od[i][1] * inv, Od[i][2] * inv, Od[i][3] * inv);
        *(float4*)&y1[((size_t)(i0 + ri) * 8 + b) * 1024 + h * 64 + tj * 4] = o;
    }
}

// ---------------------------------------------------------------------------
// Whh -> MFMA A-fragments, per-block contiguous:
// uint4 offset = g64*12288 + kt*384 + gate*128 + plane*64 + lane.
// ---------------------------------------------------------------------------
__global__ __launch_bounds__(256) void prep_whh(
    const float* __restrict__ Whh, uint4* __restrict__ outp)
{
    int idx = blockIdx.x * 256 + threadIdx.x;
    if (idx >= 393216) return;
    int lane = idx & 63;
    int rest = idx >> 6;
    int gate = rest % 3;
    int kt   = (rest / 3) & 31;
    int g64  = rest / 96;
    int n = gate * 1024 + g64 * 16 + (lane & 15);
    int k = kt * 32 + (lane >> 4) * 8;
    const float* src = Whh + (size_t)n * 1024 + k;
    float4 x0 = *(const float4*)src, x1 = *(const float4*)(src + 4);
    unsigned h[4], l[4];
    split2(x0.x, x0.y, h[0], l[0]);
    split2(x0.z, x0.w, h[1], l[1]);
    split2(x1.x, x1.y, h[2], l[2]);
    split2(x1.z, x1.w, h[3], l[3]);
    outp[((size_t)rest * 2 + 0) * 64 + lane] = make_uint4(h[0], h[1], h[2], h[3]);
    outp[((size_t)rest * 2 + 1) * 64 + lane] = make_uint4(l[0], l[1], l[2], l[3]);
}

// ---------------------------------------------------------------------------
// PERSISTENT GRU (r8 version, proven 6.75 us/step): 64 blocks x 256 threads,
// cooperative. r7 MFMA step body; h via 8B relaxed AGENT atomics; barrier =
// per-block padded flag + wave-0 64-lane spin.
// ---------------------------------------------------------------------------
__global__ __launch_bounds__(256, 1) void gru_persist2(
    const float* __restrict__ h0, float* __restrict__ hA, float* __restrict__ hB,
    const uint4* __restrict__ WhhG, const float* __restrict__ bhh,
    const float* __restrict__ xg, float* __restrict__ out,
    unsigned* __restrict__ flags)
{
    __shared__ uint4 Bf[4096];
    __shared__ float red[3][64][4];
    int tid = threadIdx.x;
    int lane = tid & 63, wv = tid >> 6;
    int g64 = blockIdx.x;

    int col = lane & 15;
    int d0 = g64 * 16 + (lane >> 4) * 4;
    bool act = (wv == 0) && (col < 8);
    float4 br4 = make_float4(0, 0, 0, 0), bz4 = br4, bn4 = br4;
    if (act) {
        br4 = *(const float4*)&bhh[d0];
        bz4 = *(const float4*)&bhh[1024 + d0];
        bn4 = *(const float4*)&bhh[2048 + d0];
    }
    const uint4* wb = WhhG + (size_t)g64 * 12288 + (wv < 3 ? wv : 0) * 128 + lane;

    for (int t = 0; t < 512; ++t) {
        const float* hi_ = (t == 0) ? h0 : ((t & 1) ? hA : hB);
        float* ho = (t & 1) ? hB : hA;

        float4 xr4, xz4, xn4;
        unsigned long long hp01 = 0, hp23 = 0;
        if (act) {
            size_t xb = ((size_t)t * 8 + col) * 3072 + d0;
            xr4 = *(const float4*)&xg[xb];
            xz4 = *(const float4*)&xg[xb + 1024];
            xn4 = *(const float4*)&xg[xb + 2048];
            hp01 = ld_coh64(hi_ + col * 1024 + d0);
            hp23 = ld_coh64(hi_ + col * 1024 + d0 + 2);
        }

        uint4 wA[16], wB[16];
        #pragma unroll
        for (int q = 0; q < 8; ++q) {
            wA[2 * q]     = wb[q * 384];
            wA[2 * q + 1] = wb[q * 384 + 64];
        }

        unsigned long long hq[16];
        #pragma unroll
        for (int i = 0; i < 4; ++i) {
            int s = i * 256 + tid;
            const float* hp = hi_ + (s & 7) * 1024 + (s >> 5) * 32 + ((s >> 3) & 3) * 8;
            #pragma unroll
            for (int q = 0; q < 4; ++q) hq[i * 4 + q] = ld_coh64(hp + q * 2);
        }
        #pragma unroll
        for (int i = 0; i < 4; ++i) {
            int s = i * 256 + tid;
            int b = s & 7, oct = (s >> 3) & 3, kt = s >> 5;
            float x[8];
            #pragma unroll
            for (int q = 0; q < 4; ++q) {
                x[2 * q]     = __uint_as_float((unsigned)(hq[i * 4 + q] & 0xffffffffu));
                x[2 * q + 1] = __uint_as_float((unsigned)(hq[i * 4 + q] >> 32));
            }
            unsigned hh[4], ll[4];
            split2(x[0], x[1], hh[0], ll[0]);
            split2(x[2], x[3], hh[1], ll[1]);
            split2(x[4], x[5], hh[2], ll[2]);
            split2(x[6], x[7], hh[3], ll[3]);
            int ln = oct * 16 + b;
            Bf[(kt * 2 + 0) * 64 + ln] = make_uint4(hh[0], hh[1], hh[2], hh[3]);
            Bf[(kt * 2 + 1) * 64 + ln] = make_uint4(ll[0], ll[1], ll[2], ll[3]);
        }
        __syncthreads();

        f32x4 acc = 0.0f;
        #define GRU_LOAD(dst, c0)                                   \
            _Pragma("unroll")                                       \
            for (int q = 0; q < 8; ++q) {                           \
                dst[2 * q]     = wb[((c0) * 8 + q) * 384];          \
                dst[2 * q + 1] = wb[((c0) * 8 + q) * 384 + 64];     \
            }
        #define GRU_COMP(src, c0)                                   \
            _Pragma("unroll")                                       \
            for (int q = 0; q < 8; ++q) {                           \
                int kt = (c0) * 8 + q;                              \
                FragU ah, al, bh, bl;                               \
                ah.u = src[2 * q]; al.u = src[2 * q + 1];           \
                bh.u = Bf[(kt * 2 + 0) * 64 + lane];                \
                bl.u = Bf[(kt * 2 + 1) * 64 + lane];                \
                acc = __builtin_amdgcn_mfma_f32_16x16x32_bf16(ah.h, bh.h, acc, 0, 0, 0); \
                acc = __builtin_amdgcn_mfma_f32_16x16x32_bf16(ah.h, bl.h, acc, 0, 0, 0); \
                acc = __builtin_amdgcn_mfma_f32_16x16x32_bf16(al.h, bh.h, acc, 0, 0, 0); \
            }
        if (wv < 3) {
            GRU_LOAD(wB, 1);
            GRU_COMP(wA, 0);
            GRU_LOAD(wA, 2);
            GRU_COMP(wB, 1);
            GRU_LOAD(wB, 3);
            GRU_COMP(wA, 2);
            GRU_COMP(wB, 3);
            *(f32x4*)&red[wv][lane][0] = acc;
        }
        #undef GRU_LOAD
        #undef GRU_COMP
        __syncthreads();

        if (act) {
            f32x4 aR = *(f32x4*)&red[0][lane][0];
            f32x4 aZ = *(f32x4*)&red[1][lane][0];
            f32x4 aN = *(f32x4*)&red[2][lane][0];
            float xr[4] = {xr4.x, xr4.y, xr4.z, xr4.w};
            float xz[4] = {xz4.x, xz4.y, xz4.z, xz4.w};
            float xn[4] = {xn4.x, xn4.y, xn4.z, xn4.w};
            float hp[4] = {__uint_as_float((unsigned)(hp01 & 0xffffffffu)),
                           __uint_as_float((unsigned)(hp01 >> 32)),
                           __uint_as_float((unsigned)(hp23 & 0xffffffffu)),
                           __uint_as_float((unsigned)(hp23 >> 32))};
            float br[4] = {br4.x, br4.y, br4.z, br4.w};
            float bz[4] = {bz4.x, bz4.y, bz4.z, bz4.w};
            float bn[4] = {bn4.x, bn4.y, bn4.z, bn4.w};
            float hn[4];
            #pragma unroll
            for (int r = 0; r < 4; ++r) {
                float rr = 1.f / (1.f + __expf(-(xr[r] + aR[r] + br[r])));
                float zz = 1.f / (1.f + __expf(-(xz[r] + aZ[r] + bz[r])));
                float nn = tanhf(xn[r] + rr * (aN[r] + bn[r]));
                hn[r] = (1.f - zz) * nn + zz * hp[r];
            }
            unsigned long long v01 = (unsigned long long)__float_as_uint(hn[0])
                                   | ((unsigned long long)__float_as_uint(hn[1]) << 32);
            unsigned long long v23 = (unsigned long long)__float_as_uint(hn[2])
                                   | ((unsigned long long)__float_as_uint(hn[3]) << 32);
            st_coh64(ho + col * 1024 + d0, v01);
            st_coh64(ho + col * 1024 + d0 + 2, v23);
            *(float4*)&out[((size_t)t * 8 + col) * 1024 + d0] =
                make_float4(hn[0], hn[1], hn[2], hn[3]);
        }

        if (t != 511) {
            __syncthreads();
            unsigned tgt = (unsigned)t + 1u;
            if (tid < 64) {
                if (tid == 0)
                    __hip_atomic_store(&flags[(size_t)g64 * 16], tgt,
                                       __ATOMIC_RELAXED, __HIP_MEMORY_SCOPE_AGENT);
                const unsigned* fp = &flags[(size_t)tid * 16];
                for (;;) {
                    unsigned f = __hip_atomic_load(fp, __ATOMIC_RELAXED,
                                                   __HIP_MEMORY_SCOPE_AGENT);
                    if (__all(f >= tgt)) break;
                }
            }
            __syncthreads();
        }
    }
}

// ---------------------------------------------------------------------------
// Fallback: one GRU step via MFMA (r7 kernel).
// ---------------------------------------------------------------------------
__global__ __launch_bounds__(192, 1) void gru_step_mfma(
    const float* __restrict__ hin, float* __restrict__ hout,
    const uint4* __restrict__ WhhG, const float* __restrict__ bhh,
    const float* __restrict__ xg, float* __restrict__ out, int t)
{
    __shared__ uint4 Bf[4096];
    __shared__ float red[3][64][4];
    int tid = threadIdx.x;
    int lane = tid & 63, wv = tid >> 6;
    int g64 = blockIdx.x;

    int col = lane & 15;
    int d0 = g64 * 16 + (lane >> 4) * 4;
    bool act = (wv == 0) && (col < 8);
    float4 xr4, xz4, xn4, hp4, br4, bz4, bn4;
    if (act) {
        size_t xb = ((size_t)t * 8 + col) * 3072 + d0;
        xr4 = *(const float4*)&xg[xb];
        xz4 = *(const float4*)&xg[xb + 1024];
        xn4 = *(const float4*)&xg[xb + 2048];
        hp4 = *(const float4*)&hin[col * 1024 + d0];
        br4 = *(const float4*)&bhh[d0];
        bz4 = *(const float4*)&bhh[1024 + d0];
        bn4 = *(const float4*)&bhh[2048 + d0];
    }

    const uint4* wb = WhhG + (size_t)g64 * 12288 + wv * 128 + lane;
    uint4 wA[16], wB[16];
    #pragma unroll
    for (int q = 0; q < 8; ++q) {
        wA[2 * q]     = wb[q * 384];
        wA[2 * q + 1] = wb[q * 384 + 64];
    }

    for (int s = tid; s < 1024; s += 192) {
        int b = s & 7, oct = (s >> 3) & 3, kt = s >> 5;
        const float* hp = hin + b * 1024 + kt * 32 + oct * 8;
        float4 x0 = *(const float4*)hp, x1 = *(const float4*)(hp + 4);
        unsigned hh[4], ll[4];
        split2(x0.x, x0.y, hh[0], ll[0]);
        split2(x0.z, x0.w, hh[1], ll[1]);
        split2(x1.x, x1.y, hh[2], ll[2]);
        split2(x1.z, x1.w, hh[3], ll[3]);
        int ln = oct * 16 + b;
        Bf[(kt * 2 + 0) * 64 + ln] = make_uint4(hh[0], hh[1], hh[2], hh[3]);
        Bf[(kt * 2 + 1) * 64 + ln] = make_uint4(ll[0], ll[1], ll[2], ll[3]);
    }
    __syncthreads();

    f32x4 acc = 0.0f;
    #define GRU_LOAD(dst, c0)                                   \
        _Pragma("unroll")                                       \
        for (int q = 0; q < 8; ++q) {                           \
            dst[2 * q]     = wb[((c0) * 8 + q) * 384];          \
            dst[2 * q + 1] = wb[((c0) * 8 + q) * 384 + 64];     \
        }
    #define GRU_COMP(src, c0)                                   \
        _Pragma("unroll")                                       \
        for (int q = 0; q < 8; ++q) {                           \
            int kt = (c0) * 8 + q;                              \
            FragU ah, al, bh, bl;                               \
            ah.u = src[2 * q]; al.u = src[2 * q + 1];           \
            bh.u = Bf[(kt * 2 + 0) * 64 + lane];                \
            bl.u = Bf[(kt * 2 + 1) * 64 + lane];                \
            acc = __builtin_amdgcn_mfma_f32_16x16x32_bf16(ah.h, bh.h, acc, 0, 0, 0); \
            acc = __builtin_amdgcn_mfma_f32_16x16x32_bf16(ah.h, bl.h, acc, 0, 0, 0); \
            acc = __builtin_amdgcn_mfma_f32_16x16x32_bf16(al.h, bh.h, acc, 0, 0, 0); \
        }
    GRU_LOAD(wB, 1);
    GRU_COMP(wA, 0);
    GRU_LOAD(wA, 2);
    GRU_COMP(wB, 1);
    GRU_LOAD(wB, 3);
    GRU_COMP(wA, 2);
    GRU_COMP(wB, 3);
    #undef GRU_LOAD
    #undef GRU_COMP

    *(f32x4*)&red[wv][lane][0] = acc;
    __syncthreads();

    if (act) {
        f32x4 aR = *(f32x4*)&red[0][lane][0];
        f32x4 aZ = *(f32x4*)&red[1][lane][0];
        f32x4 aN = *(f32x4*)&red[2][lane][0];
        float xr[4] = {xr4.x, xr4.y, xr4.z, xr4.w};
        float xz[4] = {xz4.x, xz4.y, xz4.z, xz4.w};
        float xn[4] = {xn4.x, xn4.y, xn4.z, xn4.w};
        float hp[4] = {hp4.x, hp4.y, hp4.z, hp4.w};
        float br[4] = {br4.x, br4.y, br4.z, br4.w};
        float bz[4] = {bz4.x, bz4.y, bz4.z, bz4.w};
        float bn[4] = {bn4.x, bn4.y, bn4.z, bn4.w};
        float hn[4];
        #pragma unroll
        for (int r = 0; r < 4; ++r) {
            float rr = 1.f / (1.f + __expf(-(xr[r] + aR[r] + br[r])));
            float zz = 1.f / (1.f + __expf(-(xz[r] + aZ[r] + bz[r])));
            float nn = tanhf(xn[r] + rr * (aN[r] + bn[r]));
            hn[r] = (1.f - zz) * nn + zz * hp[r];
        }
        float4 hv = make_float4(hn[0], hn[1], hn[2], hn[3]);
        *(float4*)&hout[col * 1024 + d0] = hv;
        *(float4*)&out[((size_t)t * 8 + col) * 1024 + d0] = hv;
    }
}

// ---------------------------------------------------------------------------
extern "C" void kernel_launch(void* const* d_in, const int* in_sizes, int n_in,
                              void* d_out, int out_size, void* d_ws, size_t ws_size,
                              hipStream_t stream) {
    (void)in_sizes; (void)n_in; (void)out_size; (void)ws_size;
    const float* inputs = (const float*)d_in[0];
    const float* r_in   = (const float*)d_in[1];
    const float* u_in   = (const float*)d_in[2];
    const float* v_in   = (const float*)d_in[3];
    const float* mem    = (const float*)d_in[4];
    const float* Wqkv   = (const float*)d_in[5];
    const float* Wr     = (const float*)d_in[6];
    const float* Wo     = (const float*)d_in[7];
    const float* Wih    = (const float*)d_in[8];
    const float* Whh    = (const float*)d_in[9];
    const float* bih    = (const float*)d_in[10];
    const float* bhh    = (const float*)d_in[11];
    const float* h0     = (const float*)d_in[12];
    float* out = (float*)d_out;
    float* ws = (float*)d_ws;

    float*    qkv   = ws;                           // [0, 25165824) — dead after attn
    float*    rk    = ws + 25165824;
    float*    y1    = ws + 26214400;
    float*    y2    = ws + 30408704;
    float*    xg    = ws + 34603008;                // catP overlays first 8.4M floats
    float*    hA    = ws + 47185920;
    float*    hB    = ws + 47194112;
    unsigned* WqkvP = (unsigned*)(ws + 47202304);
    unsigned* WrP   = (unsigned*)(ws + 50348032);
    unsigned* WoP   = (unsigned*)(ws + 51396608);
    unsigned* WihP  = (unsigned*)(ws + 52445184);
    unsigned* flags = (unsigned*)(ws + 55590912);   // 64 flags x 64B
    uint4*    WhhG  = (uint4*)qkv;                  // qkv[0, 3145728) floats
    unsigned* y1P   = (unsigned*)(qkv + 4194304);   // qkv[4.19M, 8.39M)
    unsigned* y2P   = (unsigned*)(qkv + 8388608);   // qkv[8.39M, 12.58M)
    unsigned* catP  = (unsigned*)xg;                // dead once qkv GEMM done

    dim3 blk(256);
    // ---- weight prep
    prep_w<true ><<<1536, blk, 0, stream>>>(Wqkv, WqkvP, 3072, 1024, 3072);
    prep_w<true ><<< 512, blk, 0, stream>>>(Wr,   WrP,   1024, 1024, 1024);
    prep_w<true ><<< 512, blk, 0, stream>>>(Wo,   WoP,   1024, 1024, 1024);
    prep_w<false><<<1536, blk, 0, stream>>>(Wih,  WihP,  3072, 1024, 1024);
    hipMemsetAsync(flags, 0, 4096, stream);   // zero flags EVERY launch (replay-safe)

    // ---- cat pre-split, then qkv = cat @ W_qkv (pre-split both sides)
    prep_cat<<<4096, blk, 0, stream>>>(mem, inputs, catP);
    gemm_pp<false><<<dim3(24, 64), blk, 0, stream>>>(
        (const uint4*)catP, (const uint4*)WqkvP, nullptr, qkv, 1024, 3072);
    // ---- rk = r @ W_r (small; old path)
    gemm_mfma<0, false><<<dim3(8, 8), blk, 0, stream>>>(
        r_in, nullptr, WrP, nullptr, rk, 1024, 1024, 1024, 1024, 1024);
    // ---- fused attention -> y1
    attn_fused<<<dim3(8, 8, 16), blk, 0, stream>>>(qkv, rk, u_in, v_in, y1);
    // ---- Whh fragment prep (qkv region now dead)
    prep_whh<<<1536, blk, 0, stream>>>(Whh, WhhG);
    // ---- y2 = y1 @ W_o
    prep_w<false><<<2048, blk, 0, stream>>>(y1, y1P, 4096, 1024, 1024);
    gemm_pp<false><<<dim3(8, 32), blk, 0, stream>>>(
        (const uint4*)y1P, (const uint4*)WoP, nullptr, y2, 1024, 1024);
    // ---- xg = y2 @ W_ih^T + b_ih
    prep_w<false><<<2048, blk, 0, stream>>>(y2, y2P, 4096, 1024, 1024);
    gemm_pp<true><<<dim3(24, 32), blk, 0, stream>>>(
        (const uint4*)y2P, (const uint4*)WihP, bih, xg, 1024, 3072);

    // ---- GRU recurrence: persistent r8 kernel; fallback: 512 launches
    {
        const float* a0 = h0; float* a1 = hA; float* a2 = hB;
        const uint4* a3 = WhhG; const float* a4 = bhh; const float* a5 = xg;
        float* a6 = out; unsigned* a7 = flags;
        void* args[8] = {&a0, &a1, &a2, &a3, &a4, &a5, &a6, &a7};
        hipError_t e = hipLaunchCooperativeKernel((void*)gru_persist2,
                                                  dim3(64), dim3(256), args, 0, stream);
        if (e != hipSuccess) {
            const float* hin = h0;
            for (int s = 0; s < 512; ++s) {
                float* hp = (s & 1) ? hB : hA;
                gru_step_mfma<<<64, dim3(192), 0, stream>>>(hin, hp, WhhG, bhh, xg, out, s);
                hin = hp;
            }
        }
    }
}

// Round 12
// 4700.700 us; speedup vs baseline: 1.4462x; 1.0039x over previous
//
#include <hip/hip_runtime.h>
#include <math.h>

// D_MODEL=1024, N_HEADS=16, D_HEAD=64, QLEN=512, MLEN=512, KLEN=1024, BATCH=8

typedef short bf16x8 __attribute__((ext_vector_type(8)));
typedef float f32x4 __attribute__((ext_vector_type(4)));

union FragU { uint4 u; bf16x8 h; };

// split two fp32 into packed bf16-hi (truncated) and bf16-lo (exact residual, truncated)
__device__ inline void split2(float x0, float x1, unsigned& hi, unsigned& lo) {
    unsigned u0 = __float_as_uint(x0), u1 = __float_as_uint(x1);
    float h0 = __uint_as_float(u0 & 0xffff0000u);
    float h1 = __uint_as_float(u1 & 0xffff0000u);
    unsigned l0 = __float_as_uint(x0 - h0), l1 = __float_as_uint(x1 - h1);
    hi = (u0 >> 16) | (u1 & 0xffff0000u);
    lo = (l0 >> 16) | (l1 & 0xffff0000u);
}

// coherent (agent-scope, cache-bypassing) 8B load/store of h state
__device__ __forceinline__ unsigned long long ld_coh64(const void* p) {
    return __hip_atomic_load((const unsigned long long*)p, __ATOMIC_RELAXED,
                             __HIP_MEMORY_SCOPE_AGENT);
}
__device__ __forceinline__ void st_coh64(void* p, unsigned long long v) {
    __hip_atomic_store((unsigned long long*)p, v, __ATOMIC_RELAXED,
                       __HIP_MEMORY_SCOPE_AGENT);
}

// async 16B global -> LDS (lds dst wave-uniform base; HW adds lane*16)
__device__ __forceinline__ void gl_lds16(const uint4* g, uint4* l) {
    __builtin_amdgcn_global_load_lds(
        (const __attribute__((address_space(1))) uint4*)g,
        (__attribute__((address_space(3))) uint4*)l, 16, 0, 0);
}

// ---------------------------------------------------------------------------
// Weight/activation prep: X (fp32, [n][k] if !TR else [k][n]) -> u32[n][K],
// 32-k tile = 8 16B slots {hi,lo,...} XOR-swizzled by (n&7).
// ---------------------------------------------------------------------------
template<bool TR>
__global__ __launch_bounds__(256) void prep_w(
    const float* __restrict__ W, unsigned* __restrict__ out, int Nr, int K, int ldw)
{
    int idx = blockIdx.x * 256 + threadIdx.x;
    int cpr = K >> 3;
    if (idx >= Nr * cpr) return;
    int n, c;
    if (TR) { n = idx % Nr; c = idx / Nr; }
    else    { c = idx % cpr; n = idx / cpr; }
    int kt = c >> 2, j = c & 3;
    int k = kt * 32 + j * 8;
    float x[8];
    #pragma unroll
    for (int i = 0; i < 8; ++i)
        x[i] = TR ? W[(size_t)(k + i) * ldw + n] : W[(size_t)n * ldw + k + i];
    unsigned h[4], l[4];
    split2(x[0], x[1], h[0], l[0]);
    split2(x[2], x[3], h[1], l[1]);
    split2(x[4], x[5], h[2], l[2]);
    split2(x[6], x[7], h[3], l[3]);
    unsigned* base = out + (size_t)n * K + kt * 32;
    *(uint4*)(base + (((2 * j) ^ (n & 7)) * 4))     = make_uint4(h[0], h[1], h[2], h[3]);
    *(uint4*)(base + (((2 * j + 1) ^ (n & 7)) * 4)) = make_uint4(l[0], l[1], l[2], l[3]);
}

// ---------------------------------------------------------------------------
// cat = [mem; inputs] -> pre-split swizzled u32[8192][1024].
// ---------------------------------------------------------------------------
__global__ __launch_bounds__(256) void prep_cat(
    const float* __restrict__ mem, const float* __restrict__ inputs,
    unsigned* __restrict__ out)
{
    int idx = blockIdx.x * 256 + threadIdx.x;
    if (idx >= 1048576) return;
    int c = idx & 127, n = idx >> 7;
    int kt = c >> 2, j = c & 3;
    int k = kt * 32 + j * 8;
    const float* src = (n < 4096) ? (mem + (size_t)n * 1024 + k)
                                  : (inputs + (size_t)(n - 4096) * 1024 + k);
    float4 x0 = *(const float4*)src, x1 = *(const float4*)(src + 4);
    unsigned h[4], l[4];
    split2(x0.x, x0.y, h[0], l[0]);
    split2(x0.z, x0.w, h[1], l[1]);
    split2(x1.x, x1.y, h[2], l[2]);
    split2(x1.z, x1.w, h[3], l[3]);
    unsigned* base = out + (size_t)n * 1024 + kt * 32;
    *(uint4*)(base + (((2 * j) ^ (n & 7)) * 4))     = make_uint4(h[0], h[1], h[2], h[3]);
    *(uint4*)(base + (((2 * j + 1) ^ (n & 7)) * 4)) = make_uint4(l[0], l[1], l[2], l[3]);
}

// ---------------------------------------------------------------------------
// Split-bf16 MFMA GEMM, BOTH operands pre-split swizzled u32[rows][K], staged
// via global_load_lds width=16. 128x128 tile, BK=32, 256 threads (2x2 waves).
// SPLITOUT: write split-swizzled u32 output (via LDS bounce) instead of fp32.
// ---------------------------------------------------------------------------
template<bool BIAS, bool SPLITOUT>
__global__ __launch_bounds__(256) void gemm_pp(
    const uint4* __restrict__ Ap4, const uint4* __restrict__ Bp4,
    const float* __restrict__ bias, float* __restrict__ C,
    unsigned* __restrict__ Cp, int K, int ldc)
{
    __shared__ uint4 SH[2048];          // Ab = SH[0:1024), Bb = SH[1024:2048)
    uint4* Ab = SH;
    uint4* Bb = SH + 1024;
    int tid = threadIdx.x;
    int lane = tid & 63, wid = tid >> 6;
    int wr = wid >> 1, wc = wid & 1;
    int n0 = blockIdx.x * 128, m0 = blockIdx.y * 128;
    int r15 = lane & 15, s = lane >> 4;
    int r4 = (lane >> 4) * 4;
    int K4 = K >> 2;                     // row stride in uint4

    f32x4 acc[4][4];
    #pragma unroll
    for (int i = 0; i < 4; ++i)
        #pragma unroll
        for (int j = 0; j < 4; ++j) acc[i][j] = 0.0f;

    for (int kt = 0; kt < (K >> 5); ++kt) {
        #pragma unroll
        for (int q = 0; q < 4; ++q) {
            int base = q * 256 + wid * 64;      // wave-uniform LDS base
            int idx  = base + lane;             // per-lane element
            int row = idx >> 3, slot = idx & 7;
            gl_lds16(Ap4 + (size_t)(m0 + row) * K4 + kt * 8 + slot, &Ab[base]);
            gl_lds16(Bp4 + (size_t)(n0 + row) * K4 + kt * 8 + slot, &Bb[base]);
        }
        __syncthreads();   // vmcnt(0) drain: tiles landed
        FragU ahi[4], alo[4], bhi[4], blo[4];
        #pragma unroll
        for (int f = 0; f < 4; ++f) {
            int ar = wr * 64 + f * 16 + r15;
            ahi[f].u = Ab[ar * 8 + ((2 * s) ^ (ar & 7))];
            alo[f].u = Ab[ar * 8 + ((2 * s + 1) ^ (ar & 7))];
            int br = wc * 64 + f * 16 + r15;
            bhi[f].u = Bb[br * 8 + ((2 * s) ^ (br & 7))];
            blo[f].u = Bb[br * 8 + ((2 * s + 1) ^ (br & 7))];
        }
        #pragma unroll
        for (int fi = 0; fi < 4; ++fi)
            #pragma unroll
            for (int fj = 0; fj < 4; ++fj) {
                acc[fi][fj] = __builtin_amdgcn_mfma_f32_16x16x32_bf16(ahi[fi].h, bhi[fj].h, acc[fi][fj], 0, 0, 0);
                acc[fi][fj] = __builtin_amdgcn_mfma_f32_16x16x32_bf16(ahi[fi].h, blo[fj].h, acc[fi][fj], 0, 0, 0);
                acc[fi][fj] = __builtin_amdgcn_mfma_f32_16x16x32_bf16(alo[fi].h, bhi[fj].h, acc[fi][fj], 0, 0, 0);
            }
        __syncthreads();
    }

    if (!SPLITOUT) {
        #pragma unroll
        for (int fj = 0; fj < 4; ++fj) {
            int n = n0 + wc * 64 + fj * 16 + r15;
            float bv = BIAS ? bias[n] : 0.f;
            #pragma unroll
            for (int fi = 0; fi < 4; ++fi) {
                int m = m0 + wr * 64 + fi * 16 + r4;
                #pragma unroll
                for (int r = 0; r < 4; ++r)
                    C[(size_t)(m + r) * ldc + n] = acc[fi][fj][r] + bv;
            }
        }
    } else {
        // bounce each 64x128 half-tile through LDS, pack split-bf16 swizzled.
        float* Cs = (float*)SH;            // 64 x 128 fp32 = 32KB
        #pragma unroll
        for (int half = 0; half < 2; ++half) {
            __syncthreads();
            if (wr == half) {
                #pragma unroll
                for (int fi = 0; fi < 4; ++fi)
                    #pragma unroll
                    for (int fj = 0; fj < 4; ++fj)
                        #pragma unroll
                        for (int r = 0; r < 4; ++r)
                            Cs[(fi * 16 + r4 + r) * 128 + wc * 64 + fj * 16 + r15] = acc[fi][fj][r];
            }
            __syncthreads();
            #pragma unroll
            for (int q = 0; q < 4; ++q) {
                int oc = q * 256 + tid;            // octet id in half-tile
                int lr = oc >> 4, oct = oc & 15;
                float4 xa = *(float4*)&Cs[lr * 128 + oct * 8];
                float4 xb = *(float4*)&Cs[lr * 128 + oct * 8 + 4];
                unsigned hw[4], lw[4];
                split2(xa.x, xa.y, hw[0], lw[0]);
                split2(xa.z, xa.w, hw[1], lw[1]);
                split2(xb.x, xb.y, hw[2], lw[2]);
                split2(xb.z, xb.w, hw[3], lw[3]);
                int m = m0 + half * 64 + lr;
                int k = n0 + oct * 8;
                int kt2 = k >> 5, j2 = (k >> 3) & 3;
                unsigned* bp = Cp + (size_t)m * ldc + kt2 * 32;
                *(uint4*)(bp + (((2 * j2)     ^ (m & 7)) * 4)) = make_uint4(hw[0], hw[1], hw[2], hw[3]);
                *(uint4*)(bp + (((2 * j2 + 1) ^ (m & 7)) * 4)) = make_uint4(lw[0], lw[1], lw[2], lw[3]);
            }
        }
    }
}

// ---------------------------------------------------------------------------
// Original split-bf16 GEMM (in-kernel A conversion) — kept for the tiny rk.
// ---------------------------------------------------------------------------
template<int AMODE, bool BIAS>
__global__ __launch_bounds__(256) void gemm_mfma(
    const float* __restrict__ A, const float* __restrict__ A2,
    const unsigned* __restrict__ Bp, const float* __restrict__ bias,
    float* __restrict__ C, int M, int N, int K, int lda, int ldc)
{
    __shared__ uint4 Ab[1024];
    __shared__ uint4 Bb[1024];
    int tid = threadIdx.x;
    int lane = tid & 63, wid = tid >> 6;
    int wr = wid >> 1, wc = wid & 1;
    int n0 = blockIdx.x * 128, m0 = blockIdx.y * 128;
    int r15 = lane & 15, s = lane >> 4;

    f32x4 acc[4][4];
    #pragma unroll
    for (int i = 0; i < 4; ++i)
        #pragma unroll
        for (int j = 0; j < 4; ++j) acc[i][j] = 0.0f;

    for (int kt = 0; kt < (K >> 5); ++kt) {
        int k0 = kt * 32;
        #pragma unroll
        for (int q = 0; q < 2; ++q) {
            int idx = q * 256 + tid;
            int row = idx >> 2, j = idx & 3;
            const float* ap;
            if (AMODE == 1) {
                int gm = m0 + row;
                ap = (gm < 4096) ? (A + (size_t)gm * lda) : (A2 + (size_t)(gm - 4096) * lda);
            } else {
                ap = A + (size_t)(m0 + row) * lda;
            }
            float4 x0 = *(const float4*)(ap + k0 + j * 8);
            float4 x1 = *(const float4*)(ap + k0 + j * 8 + 4);
            unsigned h[4], l[4];
            split2(x0.x, x0.y, h[0], l[0]);
            split2(x0.z, x0.w, h[1], l[1]);
            split2(x1.x, x1.y, h[2], l[2]);
            split2(x1.z, x1.w, h[3], l[3]);
            Ab[row * 8 + (((2 * j) ^ (row & 7)))]     = make_uint4(h[0], h[1], h[2], h[3]);
            Ab[row * 8 + (((2 * j + 1) ^ (row & 7)))] = make_uint4(l[0], l[1], l[2], l[3]);
        }
        #pragma unroll
        for (int q = 0; q < 4; ++q) {
            int idx = q * 256 + tid;
            int row = idx >> 3, slot = idx & 7;
            Bb[idx] = *(const uint4*)(Bp + (size_t)(n0 + row) * K + k0 + slot * 4);
        }
        __syncthreads();
        FragU ahi[4], alo[4], bhi[4], blo[4];
        #pragma unroll
        for (int f = 0; f < 4; ++f) {
            int ar = wr * 64 + f * 16 + r15;
            ahi[f].u = Ab[ar * 8 + ((2 * s) ^ (ar & 7))];
            alo[f].u = Ab[ar * 8 + ((2 * s + 1) ^ (ar & 7))];
            int br = wc * 64 + f * 16 + r15;
            bhi[f].u = Bb[br * 8 + ((2 * s) ^ (br & 7))];
            blo[f].u = Bb[br * 8 + ((2 * s + 1) ^ (br & 7))];
        }
        #pragma unroll
        for (int fi = 0; fi < 4; ++fi)
            #pragma unroll
            for (int fj = 0; fj < 4; ++fj) {
                acc[fi][fj] = __builtin_amdgcn_mfma_f32_16x16x32_bf16(ahi[fi].h, bhi[fj].h, acc[fi][fj], 0, 0, 0);
                acc[fi][fj] = __builtin_amdgcn_mfma_f32_16x16x32_bf16(ahi[fi].h, blo[fj].h, acc[fi][fj], 0, 0, 0);
                acc[fi][fj] = __builtin_amdgcn_mfma_f32_16x16x32_bf16(alo[fi].h, bhi[fj].h, acc[fi][fj], 0, 0, 0);
            }
        __syncthreads();
    }
    int r4 = (lane >> 4) * 4;
    #pragma unroll
    for (int fj = 0; fj < 4; ++fj) {
        int n = n0 + wc * 64 + fj * 16 + r15;
        float bv = BIAS ? bias[n] : 0.f;
        #pragma unroll
        for (int fi = 0; fi < 4; ++fi) {
            int m = m0 + wr * 64 + fi * 16 + r4;
            #pragma unroll
            for (int r = 0; r < 4; ++r)
                C[(size_t)(m + r) * ldc + n] = acc[fi][fj][r] + bv;
        }
    }
}

// ---------------------------------------------------------------------------
// Fused TXL attention (fp32). Writes y1 DIRECTLY in split-swizzled form (y1P)
// — same split2 math as prep_w, so downstream GEMM sees identical bits.
// ---------------------------------------------------------------------------
__global__ __launch_bounds__(256) void attn_fused(
    const float* __restrict__ qkv, const float* __restrict__ rk,
    const float* __restrict__ u_, const float* __restrict__ v_,
    unsigned* __restrict__ y1P)
{
    __shared__ float qu[64][68], qv[64][68], Kt[64][68], Vt[64][68];
    __shared__ float RKs[128][68];
    __shared__ float S[64][68];
    __shared__ float mrow[64], lrow[64], scalef[64];
    __shared__ float pmax[64][16], psum[64][16];

    int tid = threadIdx.x;
    int it = blockIdx.x, b = blockIdx.y, h = blockIdx.z;
    int i0 = it * 64;
    int ti = tid >> 4, tj = tid & 15;

    {
        int r = tid >> 2, c0 = (tid & 3) * 16;
        size_t base = ((size_t)(i0 + r + 512) * 8 + b) * 3072 + h * 64;
        #pragma unroll
        for (int q = 0; q < 4; ++q) {
            int c = c0 + q * 4;
            float4 qq = *(const float4*)&qkv[base + c];
            float4 uu = *(const float4*)&u_[h * 64 + c];
            float4 vv = *(const float4*)&v_[h * 64 + c];
            *(float4*)&qu[r][c] = make_float4(qq.x + uu.x, qq.y + uu.y, qq.z + uu.z, qq.w + uu.w);
            *(float4*)&qv[r][c] = make_float4(qq.x + vv.x, qq.y + vv.y, qq.z + vv.z, qq.w + vv.w);
        }
    }
    if (tid < 64) { mrow[tid] = -1e30f; lrow[tid] = 0.f; }

    float Od[4][4] = {};
    int njt = it + 9;

    for (int jt = 0; jt < njt; ++jt) {
        int j0 = jt * 64;
        __syncthreads();
        {
            int r = tid >> 2, c0 = (tid & 3) * 16;
            size_t kb = ((size_t)(j0 + r) * 8 + b) * 3072 + 1024 + h * 64;
            #pragma unroll
            for (int q = 0; q < 4; ++q) {
                int c = c0 + q * 4;
                *(float4*)&Kt[r][c] = *(const float4*)&qkv[kb + c];
                *(float4*)&Vt[r][c] = *(const float4*)&qkv[kb + 1024 + c];
            }
        }
        {
            int r2 = tid >> 1, c0 = (tid & 1) * 32;
            int jj = j0 - i0 + 448 + r2;
            jj = jj < 0 ? 0 : (jj > 1023 ? 1023 : jj);
            size_t rb = (size_t)jj * 1024 + h * 64;
            #pragma unroll
            for (int q = 0; q < 8; ++q) {
                int c = c0 + q * 4;
                *(float4*)&RKs[r2][c] = *(const float4*)&rk[rb + c];
            }
        }
        __syncthreads();

        float acc[4][4] = {};
        int jlb = (tj - ti) * 4 + 60;
        #pragma unroll 4
        for (int d4 = 0; d4 < 64; d4 += 4) {
            float4 Aq[4], Cq[4], Kv[4], Rv[7];
            #pragma unroll
            for (int i = 0; i < 4; ++i) {
                Aq[i] = *(float4*)&qu[ti * 4 + i][d4];
                Cq[i] = *(float4*)&qv[ti * 4 + i][d4];
                Kv[i] = *(float4*)&Kt[tj * 4 + i][d4];
            }
            #pragma unroll
            for (int t = 0; t < 7; ++t)
                Rv[t] = *(float4*)&RKs[jlb + t][d4];
            #pragma unroll
            for (int i = 0; i < 4; ++i)
                #pragma unroll
                for (int j = 0; j < 4; ++j) {
                    float4 kk = Kv[j];
                    float4 rr = Rv[j - i + 3];
                    acc[i][j] += Aq[i].x * kk.x + Aq[i].y * kk.y + Aq[i].z * kk.z + Aq[i].w * kk.w
                               + Cq[i].x * rr.x + Cq[i].y * rr.y + Cq[i].z * rr.z + Cq[i].w * rr.w;
                }
        }
        #pragma unroll
        for (int i = 0; i < 4; ++i) {
            int gi = i0 + ti * 4 + i;
            float mx = -1e30f;
            #pragma unroll
            for (int j = 0; j < 4; ++j) {
                int gj = j0 + tj * 4 + j;
                float vS = acc[i][j] * 0.125f;
                if (gj > gi + 512) vS = -1e30f;
                acc[i][j] = vS;
                mx = fmaxf(mx, vS);
            }
            pmax[ti * 4 + i][tj] = mx;
        }
        __syncthreads();
        if (tid < 64) {
            float mo = mrow[tid], mn = mo;
            #pragma unroll
            for (int t = 0; t < 16; ++t) mn = fmaxf(mn, pmax[tid][t]);
            mrow[tid] = mn;
            scalef[tid] = __expf(mo - mn);
        }
        __syncthreads();
        #pragma unroll
        for (int i = 0; i < 4; ++i) {
            int ri = ti * 4 + i;
            float mn = mrow[ri];
            float4 pv;
            pv.x = __expf(acc[i][0] - mn);
            pv.y = __expf(acc[i][1] - mn);
            pv.z = __expf(acc[i][2] - mn);
            pv.w = __expf(acc[i][3] - mn);
            *(float4*)&S[ri][tj * 4] = pv;
            psum[ri][tj] = pv.x + pv.y + pv.z + pv.w;
            float scl = scalef[ri];
            #pragma unroll
            for (int j2 = 0; j2 < 4; ++j2) Od[i][j2] *= scl;
        }
        __syncthreads();
        if (tid < 64) {
            float s = 0.f;
            #pragma unroll
            for (int t = 0; t < 16; ++t) s += psum[tid][t];
            lrow[tid] = lrow[tid] * scalef[tid] + s;
        }
        #pragma unroll 4
        for (int jb = 0; jb < 64; jb += 4) {
            float4 p0 = *(float4*)&S[ti * 4 + 0][jb];
            float4 p1 = *(float4*)&S[ti * 4 + 1][jb];
            float4 p2 = *(float4*)&S[ti * 4 + 2][jb];
            float4 p3 = *(float4*)&S[ti * 4 + 3][jb];
            float4 v0 = *(float4*)&Vt[jb + 0][tj * 4];
            float4 v1 = *(float4*)&Vt[jb + 1][tj * 4];
            float4 v2 = *(float4*)&Vt[jb + 2][tj * 4];
            float4 v3 = *(float4*)&Vt[jb + 3][tj * 4];
            float4 pr[4] = {p0, p1, p2, p3};
            #pragma unroll
            for (int i = 0; i < 4; ++i) {
                Od[i][0] += pr[i].x * v0.x + pr[i].y * v1.x + pr[i].z * v2.x + pr[i].w * v3.x;
                Od[i][1] += pr[i].x * v0.y + pr[i].y * v1.y + pr[i].z * v2.y + pr[i].w * v3.y;
                Od[i][2] += pr[i].x * v0.z + pr[i].y * v1.z + pr[i].z * v2.z + pr[i].w * v3.z;
                Od[i][3] += pr[i].x * v0.w + pr[i].y * v1.w + pr[i].z * v2.w + pr[i].w * v3.w;
            }
        }
    }
    __syncthreads();
    // epilogue: write split-swizzled y1P[n][k], n=(i0+ri)*8+b, k=h*64+tj*4..+3
    #pragma unroll
    for (int i = 0; i < 4; ++i) {
        int ri = ti * 4 + i;
        float inv = 1.f / lrow[ri];
        float4 o = make_float4(Od[i][0] * inv, Od[i][1] * inv, Od[i][2] * inv, Od[i][3] * inv);
        int n = (i0 + ri) * 8 + b;
        unsigned hw0, hw1, lw0, lw1;
        split2(o.x, o.y, hw0, lw0);
        split2(o.z, o.w, hw1, lw1);
        int kt2 = 2 * h + (tj >> 3);
        int j2 = (tj >> 1) & 3;
        int wo = (tj & 1) * 2;
        unsigned* bp = y1P + (size_t)n * 1024 + kt2 * 32;
        *(uint2*)(bp + (((2 * j2)     ^ (n & 7)) * 4) + wo) = make_uint2(hw0, hw1);
        *(uint2*)(bp + (((2 * j2 + 1) ^ (n & 7)) * 4) + wo) = make_uint2(lw0, lw1);
    }
}

// ---------------------------------------------------------------------------
// Whh -> MFMA A-fragments, per-block contiguous:
// uint4 offset = g64*12288 + kt*384 + gate*128 + plane*64 + lane.
// ---------------------------------------------------------------------------
__global__ __launch_bounds__(256) void prep_whh(
    const float* __restrict__ Whh, uint4* __restrict__ outp)
{
    int idx = blockIdx.x * 256 + threadIdx.x;
    if (idx >= 393216) return;
    int lane = idx & 63;
    int rest = idx >> 6;
    int gate = rest % 3;
    int kt   = (rest / 3) & 31;
    int g64  = rest / 96;
    int n = gate * 1024 + g64 * 16 + (lane & 15);
    int k = kt * 32 + (lane >> 4) * 8;
    const float* src = Whh + (size_t)n * 1024 + k;
    float4 x0 = *(const float4*)src, x1 = *(const float4*)(src + 4);
    unsigned h[4], l[4];
    split2(x0.x, x0.y, h[0], l[0]);
    split2(x0.z, x0.w, h[1], l[1]);
    split2(x1.x, x1.y, h[2], l[2]);
    split2(x1.z, x1.w, h[3], l[3]);
    outp[((size_t)rest * 2 + 0) * 64 + lane] = make_uint4(h[0], h[1], h[2], h[3]);
    outp[((size_t)rest * 2 + 1) * 64 + lane] = make_uint4(l[0], l[1], l[2], l[3]);
}

// ---------------------------------------------------------------------------
// PERSISTENT GRU (r8 version, proven 6.75 us/step).
// ---------------------------------------------------------------------------
__global__ __launch_bounds__(256, 1) void gru_persist2(
    const float* __restrict__ h0, float* __restrict__ hA, float* __restrict__ hB,
    const uint4* __restrict__ WhhG, const float* __restrict__ bhh,
    const float* __restrict__ xg, float* __restrict__ out,
    unsigned* __restrict__ flags)
{
    __shared__ uint4 Bf[4096];
    __shared__ float red[3][64][4];
    int tid = threadIdx.x;
    int lane = tid & 63, wv = tid >> 6;
    int g64 = blockIdx.x;

    int col = lane & 15;
    int d0 = g64 * 16 + (lane >> 4) * 4;
    bool act = (wv == 0) && (col < 8);
    float4 br4 = make_float4(0, 0, 0, 0), bz4 = br4, bn4 = br4;
    if (act) {
        br4 = *(const float4*)&bhh[d0];
        bz4 = *(const float4*)&bhh[1024 + d0];
        bn4 = *(const float4*)&bhh[2048 + d0];
    }
    const uint4* wb = WhhG + (size_t)g64 * 12288 + (wv < 3 ? wv : 0) * 128 + lane;

    for (int t = 0; t < 512; ++t) {
        const float* hi_ = (t == 0) ? h0 : ((t & 1) ? hA : hB);
        float* ho = (t & 1) ? hB : hA;

        float4 xr4, xz4, xn4;
        unsigned long long hp01 = 0, hp23 = 0;
        if (act) {
            size_t xb = ((size_t)t * 8 + col) * 3072 + d0;
            xr4 = *(const float4*)&xg[xb];
            xz4 = *(const float4*)&xg[xb + 1024];
            xn4 = *(const float4*)&xg[xb + 2048];
            hp01 = ld_coh64(hi_ + col * 1024 + d0);
            hp23 = ld_coh64(hi_ + col * 1024 + d0 + 2);
        }

        uint4 wA[16], wB[16];
        #pragma unroll
        for (int q = 0; q < 8; ++q) {
            wA[2 * q]     = wb[q * 384];
            wA[2 * q + 1] = wb[q * 384 + 64];
        }

        unsigned long long hq[16];
        #pragma unroll
        for (int i = 0; i < 4; ++i) {
            int s = i * 256 + tid;
            const float* hp = hi_ + (s & 7) * 1024 + (s >> 5) * 32 + ((s >> 3) & 3) * 8;
            #pragma unroll
            for (int q = 0; q < 4; ++q) hq[i * 4 + q] = ld_coh64(hp + q * 2);
        }
        #pragma unroll
        for (int i = 0; i < 4; ++i) {
            int s = i * 256 + tid;
            int b = s & 7, oct = (s >> 3) & 3, kt = s >> 5;
            float x[8];
            #pragma unroll
            for (int q = 0; q < 4; ++q) {
                x[2 * q]     = __uint_as_float((unsigned)(hq[i * 4 + q] & 0xffffffffu));
                x[2 * q + 1] = __uint_as_float((unsigned)(hq[i * 4 + q] >> 32));
            }
            unsigned hh[4], ll[4];
            split2(x[0], x[1], hh[0], ll[0]);
            split2(x[2], x[3], hh[1], ll[1]);
            split2(x[4], x[5], hh[2], ll[2]);
            split2(x[6], x[7], hh[3], ll[3]);
            int ln = oct * 16 + b;
            Bf[(kt * 2 + 0) * 64 + ln] = make_uint4(hh[0], hh[1], hh[2], hh[3]);
            Bf[(kt * 2 + 1) * 64 + ln] = make_uint4(ll[0], ll[1], ll[2], ll[3]);
        }
        __syncthreads();

        f32x4 acc = 0.0f;
        #define GRU_LOAD(dst, c0)                                   \
            _Pragma("unroll")                                       \
            for (int q = 0; q < 8; ++q) {                           \
                dst[2 * q]     = wb[((c0) * 8 + q) * 384];          \
                dst[2 * q + 1] = wb[((c0) * 8 + q) * 384 + 64];     \
            }
        #define GRU_COMP(src, c0)                                   \
            _Pragma("unroll")                                       \
            for (int q = 0; q < 8; ++q) {                           \
                int kt = (c0) * 8 + q;                              \
                FragU ah, al, bh, bl;                               \
                ah.u = src[2 * q]; al.u = src[2 * q + 1];           \
                bh.u = Bf[(kt * 2 + 0) * 64 + lane];                \
                bl.u = Bf[(kt * 2 + 1) * 64 + lane];                \
                acc = __builtin_amdgcn_mfma_f32_16x16x32_bf16(ah.h, bh.h, acc, 0, 0, 0); \
                acc = __builtin_amdgcn_mfma_f32_16x16x32_bf16(ah.h, bl.h, acc, 0, 0, 0); \
                acc = __builtin_amdgcn_mfma_f32_16x16x32_bf16(al.h, bh.h, acc, 0, 0, 0); \
            }
        if (wv < 3) {
            GRU_LOAD(wB, 1);
            GRU_COMP(wA, 0);
            GRU_LOAD(wA, 2);
            GRU_COMP(wB, 1);
            GRU_LOAD(wB, 3);
            GRU_COMP(wA, 2);
            GRU_COMP(wB, 3);
            *(f32x4*)&red[wv][lane][0] = acc;
        }
        #undef GRU_LOAD
        #undef GRU_COMP
        __syncthreads();

        if (act) {
            f32x4 aR = *(f32x4*)&red[0][lane][0];
            f32x4 aZ = *(f32x4*)&red[1][lane][0];
            f32x4 aN = *(f32x4*)&red[2][lane][0];
            float xr[4] = {xr4.x, xr4.y, xr4.z, xr4.w};
            float xz[4] = {xz4.x, xz4.y, xz4.z, xz4.w};
            float xn[4] = {xn4.x, xn4.y, xn4.z, xn4.w};
            float hp[4] = {__uint_as_float((unsigned)(hp01 & 0xffffffffu)),
                           __uint_as_float((unsigned)(hp01 >> 32)),
                           __uint_as_float((unsigned)(hp23 & 0xffffffffu)),
                           __uint_as_float((unsigned)(hp23 >> 32))};
            float br[4] = {br4.x, br4.y, br4.z, br4.w};
            float bz[4] = {bz4.x, bz4.y, bz4.z, bz4.w};
            float bn[4] = {bn4.x, bn4.y, bn4.z, bn4.w};
            float hn[4];
            #pragma unroll
            for (int r = 0; r < 4; ++r) {
                float rr = 1.f / (1.f + __expf(-(xr[r] + aR[r] + br[r])));
                float zz = 1.f / (1.f + __expf(-(xz[r] + aZ[r] + bz[r])));
                float nn = tanhf(xn[r] + rr * (aN[r] + bn[r]));
                hn[r] = (1.f - zz) * nn + zz * hp[r];
            }
            unsigned long long v01 = (unsigned long long)__float_as_uint(hn[0])
                                   | ((unsigned long long)__float_as_uint(hn[1]) << 32);
            unsigned long long v23 = (unsigned long long)__float_as_uint(hn[2])
                                   | ((unsigned long long)__float_as_uint(hn[3]) << 32);
            st_coh64(ho + col * 1024 + d0, v01);
            st_coh64(ho + col * 1024 + d0 + 2, v23);
            *(float4*)&out[((size_t)t * 8 + col) * 1024 + d0] =
                make_float4(hn[0], hn[1], hn[2], hn[3]);
        }

        if (t != 511) {
            __syncthreads();
            unsigned tgt = (unsigned)t + 1u;
            if (tid < 64) {
                if (tid == 0)
                    __hip_atomic_store(&flags[(size_t)g64 * 16], tgt,
                                       __ATOMIC_RELAXED, __HIP_MEMORY_SCOPE_AGENT);
                const unsigned* fp = &flags[(size_t)tid * 16];
                for (;;) {
                    unsigned f = __hip_atomic_load(fp, __ATOMIC_RELAXED,
                                                   __HIP_MEMORY_SCOPE_AGENT);
                    if (__all(f >= tgt)) break;
                }
            }
            __syncthreads();
        }
    }
}

// ---------------------------------------------------------------------------
// Fallback: one GRU step via MFMA (r7 kernel).
// ---------------------------------------------------------------------------
__global__ __launch_bounds__(192, 1) void gru_step_mfma(
    const float* __restrict__ hin, float* __restrict__ hout,
    const uint4* __restrict__ WhhG, const float* __restrict__ bhh,
    const float* __restrict__ xg, float* __restrict__ out, int t)
{
    __shared__ uint4 Bf[4096];
    __shared__ float red[3][64][4];
    int tid = threadIdx.x;
    int lane = tid & 63, wv = tid >> 6;
    int g64 = blockIdx.x;

    int col = lane & 15;
    int d0 = g64 * 16 + (lane >> 4) * 4;
    bool act = (wv == 0) && (col < 8);
    float4 xr4, xz4, xn4, hp4, br4, bz4, bn4;
    if (act) {
        size_t xb = ((size_t)t * 8 + col) * 3072 + d0;
        xr4 = *(const float4*)&xg[xb];
        xz4 = *(const float4*)&xg[xb + 1024];
        xn4 = *(const float4*)&xg[xb + 2048];
        hp4 = *(const float4*)&hin[col * 1024 + d0];
        br4 = *(const float4*)&bhh[d0];
        bz4 = *(const float4*)&bhh[1024 + d0];
        bn4 = *(const float4*)&bhh[2048 + d0];
    }

    const uint4* wb = WhhG + (size_t)g64 * 12288 + wv * 128 + lane;
    uint4 wA[16], wB[16];
    #pragma unroll
    for (int q = 0; q < 8; ++q) {
        wA[2 * q]     = wb[q * 384];
        wA[2 * q + 1] = wb[q * 384 + 64];
    }

    for (int s = tid; s < 1024; s += 192) {
        int b = s & 7, oct = (s >> 3) & 3, kt = s >> 5;
        const float* hp = hin + b * 1024 + kt * 32 + oct * 8;
        float4 x0 = *(const float4*)hp, x1 = *(const float4*)(hp + 4);
        unsigned hh[4], ll[4];
        split2(x0.x, x0.y, hh[0], ll[0]);
        split2(x0.z, x0.w, hh[1], ll[1]);
        split2(x1.x, x1.y, hh[2], ll[2]);
        split2(x1.z, x1.w, hh[3], ll[3]);
        int ln = oct * 16 + b;
        Bf[(kt * 2 + 0) * 64 + ln] = make_uint4(hh[0], hh[1], hh[2], hh[3]);
        Bf[(kt * 2 + 1) * 64 + ln] = make_uint4(ll[0], ll[1], ll[2], ll[3]);
    }
    __syncthreads();

    f32x4 acc = 0.0f;
    #define GRU_LOAD(dst, c0)                                   \
        _Pragma("unroll")                                       \
        for (int q = 0; q < 8; ++q) {                           \
            dst[2 * q]     = wb[((c0) * 8 + q) * 384];          \
            dst[2 * q + 1] = wb[((c0) * 8 + q) * 384 + 64];     \
        }
    #define GRU_COMP(src, c0)                                   \
        _Pragma("unroll")                                       \
        for (int q = 0; q < 8; ++q) {                           \
            int kt = (c0) * 8 + q;                              \
            FragU ah, al, bh, bl;                               \
            ah.u = src[2 * q]; al.u = src[2 * q + 1];           \
            bh.u = Bf[(kt * 2 + 0) * 64 + lane];                \
            bl.u = Bf[(kt * 2 + 1) * 64 + lane];                \
            acc = __builtin_amdgcn_mfma_f32_16x16x32_bf16(ah.h, bh.h, acc, 0, 0, 0); \
            acc = __builtin_amdgcn_mfma_f32_16x16x32_bf16(ah.h, bl.h, acc, 0, 0, 0); \
            acc = __builtin_amdgcn_mfma_f32_16x16x32_bf16(al.h, bh.h, acc, 0, 0, 0); \
        }
    GRU_LOAD(wB, 1);
    GRU_COMP(wA, 0);
    GRU_LOAD(wA, 2);
    GRU_COMP(wB, 1);
    GRU_LOAD(wB, 3);
    GRU_COMP(wA, 2);
    GRU_COMP(wB, 3);
    #undef GRU_LOAD
    #undef GRU_COMP

    *(f32x4*)&red[wv][lane][0] = acc;
    __syncthreads();

    if (act) {
        f32x4 aR = *(f32x4*)&red[0][lane][0];
        f32x4 aZ = *(f32x4*)&red[1][lane][0];
        f32x4 aN = *(f32x4*)&red[2][lane][0];
        float xr[4] = {xr4.x, xr4.y, xr4.z, xr4.w};
        float xz[4] = {xz4.x, xz4.y, xz4.z, xz4.w};
        float xn[4] = {xn4.x, xn4.y, xn4.z, xn4.w};
        float hp[4] = {hp4.x, hp4.y, hp4.z, hp4.w};
        float br[4] = {br4.x, br4.y, br4.z, br4.w};
        float bz[4] = {bz4.x, bz4.y, bz4.z, bz4.w};
        float bn[4] = {bn4.x, bn4.y, bn4.z, bn4.w};
        float hn[4];
        #pragma unroll
        for (int r = 0; r < 4; ++r) {
            float rr = 1.f / (1.f + __expf(-(xr[r] + aR[r] + br[r])));
            float zz = 1.f / (1.f + __expf(-(xz[r] + aZ[r] + bz[r])));
            float nn = tanhf(xn[r] + rr * (aN[r] + bn[r]));
            hn[r] = (1.f - zz) * nn + zz * hp[r];
        }
        float4 hv = make_float4(hn[0], hn[1], hn[2], hn[3]);
        *(float4*)&hout[col * 1024 + d0] = hv;
        *(float4*)&out[((size_t)t * 8 + col) * 1024 + d0] = hv;
    }
}

// ---------------------------------------------------------------------------
extern "C" void kernel_launch(void* const* d_in, const int* in_sizes, int n_in,
                              void* d_out, int out_size, void* d_ws, size_t ws_size,
                              hipStream_t stream) {
    (void)in_sizes; (void)n_in; (void)out_size; (void)ws_size;
    const float* inputs = (const float*)d_in[0];
    const float* r_in   = (const float*)d_in[1];
    const float* u_in   = (const float*)d_in[2];
    const float* v_in   = (const float*)d_in[3];
    const float* mem    = (const float*)d_in[4];
    const float* Wqkv   = (const float*)d_in[5];
    const float* Wr     = (const float*)d_in[6];
    const float* Wo     = (const float*)d_in[7];
    const float* Wih    = (const float*)d_in[8];
    const float* Whh    = (const float*)d_in[9];
    const float* bih    = (const float*)d_in[10];
    const float* bhh    = (const float*)d_in[11];
    const float* h0     = (const float*)d_in[12];
    float* out = (float*)d_out;
    float* ws = (float*)d_ws;

    float*    qkv   = ws;                           // [0, 25165824) — dead after attn
    float*    rk    = ws + 25165824;
    unsigned* y1P   = (unsigned*)(ws + 26214400);   // split y1, [4096][1024] u32
    unsigned* y2P   = (unsigned*)(ws + 30408704);   // split y2, [4096][1024] u32
    float*    xg    = ws + 34603008;                // catP overlays (dead before xg write)
    float*    hA    = ws + 47185920;
    float*    hB    = ws + 47194112;
    unsigned* WqkvP = (unsigned*)(ws + 47202304);
    unsigned* WrP   = (unsigned*)(ws + 50348032);
    unsigned* WoP   = (unsigned*)(ws + 51396608);
    unsigned* WihP  = (unsigned*)(ws + 52445184);
    unsigned* flags = (unsigned*)(ws + 55590912);   // 64 flags x 64B
    uint4*    WhhG  = (uint4*)qkv;                  // written AFTER attn
    unsigned* catP  = (unsigned*)xg;                // dead once qkv GEMMs done

    dim3 blk(256);
    // ---- weight prep
    prep_w<true ><<<1536, blk, 0, stream>>>(Wqkv, WqkvP, 3072, 1024, 3072);
    prep_w<true ><<< 512, blk, 0, stream>>>(Wr,   WrP,   1024, 1024, 1024);
    prep_w<true ><<< 512, blk, 0, stream>>>(Wo,   WoP,   1024, 1024, 1024);
    prep_w<false><<<1536, blk, 0, stream>>>(Wih,  WihP,  3072, 1024, 1024);
    hipMemsetAsync(flags, 0, 4096, stream);   // zero flags EVERY launch (replay-safe)

    // ---- cat pre-split; qkv GEMM skips the dead Q-region of mem rows:
    //      call A: rows 0..4095 (mem), cols 1024..3071 (K,V only)
    //      call B: rows 4096..8191 (inputs), all 3072 cols
    prep_cat<<<4096, blk, 0, stream>>>(mem, inputs, catP);
    gemm_pp<false, false><<<dim3(16, 32), blk, 0, stream>>>(
        (const uint4*)catP, (const uint4*)WqkvP + 1024 * 256, nullptr,
        qkv + 1024, nullptr, 1024, 3072);
    gemm_pp<false, false><<<dim3(24, 32), blk, 0, stream>>>(
        (const uint4*)catP + 4096 * 256, (const uint4*)WqkvP, nullptr,
        qkv + (size_t)4096 * 3072, nullptr, 1024, 3072);
    // ---- rk = r @ W_r (small; old path)
    gemm_mfma<0, false><<<dim3(8, 8), blk, 0, stream>>>(
        r_in, nullptr, WrP, nullptr, rk, 1024, 1024, 1024, 1024, 1024);
    // ---- fused attention -> y1P (split-swizzled directly)
    attn_fused<<<dim3(8, 8, 16), blk, 0, stream>>>(qkv, rk, u_in, v_in, y1P);
    // ---- Whh fragment prep (qkv region now dead)
    prep_whh<<<1536, blk, 0, stream>>>(Whh, WhhG);
    // ---- y2P = (y1 @ W_o) split-swizzled directly (no fp32 y2, no prep pass)
    gemm_pp<false, true><<<dim3(8, 32), blk, 0, stream>>>(
        (const uint4*)y1P, (const uint4*)WoP, nullptr, nullptr, y2P, 1024, 1024);
    // ---- xg = y2 @ W_ih^T + b_ih (fp32 out, consumed by GRU)
    gemm_pp<true, false><<<dim3(24, 32), blk, 0, stream>>>(
        (const uint4*)y2P, (const uint4*)WihP, bih, xg, nullptr, 1024, 3072);

    // ---- GRU recurrence: persistent r8 kernel; fallback: 512 launches
    {
        const float* a0 = h0; float* a1 = hA; float* a2 = hB;
        const uint4* a3 = WhhG; const float* a4 = bhh; const float* a5 = xg;
        float* a6 = out; unsigned* a7 = flags;
        void* args[8] = {&a0, &a1, &a2, &a3, &a4, &a5, &a6, &a7};
        hipError_t e = hipLaunchCooperativeKernel((void*)gru_persist2,
                                                  dim3(64), dim3(256), args, 0, stream);
        if (e != hipSuccess) {
            const float* hin = h0;
            for (int s = 0; s < 512; ++s) {
                float* hp = (s & 1) ? hB : hA;
                gru_step_mfma<<<64, dim3(192), 0, stream>>>(hin, hp, WhhG, bhh, xg, out, s);
                hin = hp;
            }
        }
    }
}

// Round 13
// 4672.166 us; speedup vs baseline: 1.4551x; 1.0061x over previous
//
#include <hip/hip_runtime.h>
#include <math.h>

// D_MODEL=1024, N_HEADS=16, D_HEAD=64, QLEN=512, MLEN=512, KLEN=1024, BATCH=8

typedef short bf16x8 __attribute__((ext_vector_type(8)));
typedef float f32x4 __attribute__((ext_vector_type(4)));

union FragU { uint4 u; bf16x8 h; };

// split two fp32 into packed bf16-hi (truncated) and bf16-lo (exact residual, truncated)
__device__ inline void split2(float x0, float x1, unsigned& hi, unsigned& lo) {
    unsigned u0 = __float_as_uint(x0), u1 = __float_as_uint(x1);
    float h0 = __uint_as_float(u0 & 0xffff0000u);
    float h1 = __uint_as_float(u1 & 0xffff0000u);
    unsigned l0 = __float_as_uint(x0 - h0), l1 = __float_as_uint(x1 - h1);
    hi = (u0 >> 16) | (u1 & 0xffff0000u);
    lo = (l0 >> 16) | (l1 & 0xffff0000u);
}

// coherent (agent-scope, cache-bypassing) 8B load/store of h state
__device__ __forceinline__ unsigned long long ld_coh64(const void* p) {
    return __hip_atomic_load((const unsigned long long*)p, __ATOMIC_RELAXED,
                             __HIP_MEMORY_SCOPE_AGENT);
}
__device__ __forceinline__ void st_coh64(void* p, unsigned long long v) {
    __hip_atomic_store((unsigned long long*)p, v, __ATOMIC_RELAXED,
                       __HIP_MEMORY_SCOPE_AGENT);
}

// async 16B global -> LDS (lds dst wave-uniform base; HW adds lane*16)
__device__ __forceinline__ void gl_lds16(const uint4* g, uint4* l) {
    __builtin_amdgcn_global_load_lds(
        (const __attribute__((address_space(1))) uint4*)g,
        (__attribute__((address_space(3))) uint4*)l, 16, 0, 0);
}

// split-store one 8-float octet to out[n][K] swizzled layout
__device__ __forceinline__ void split_store8(
    const float* x, unsigned* out, int n, int K, int kt, int j)
{
    unsigned h[4], l[4];
    split2(x[0], x[1], h[0], l[0]);
    split2(x[2], x[3], h[1], l[1]);
    split2(x[4], x[5], h[2], l[2]);
    split2(x[6], x[7], h[3], l[3]);
    unsigned* base = out + (size_t)n * K + kt * 32;
    *(uint4*)(base + (((2 * j) ^ (n & 7)) * 4))     = make_uint4(h[0], h[1], h[2], h[3]);
    *(uint4*)(base + (((2 * j + 1) ^ (n & 7)) * 4)) = make_uint4(l[0], l[1], l[2], l[3]);
}

// ---------------------------------------------------------------------------
// ONE fused prep kernel: cat(gather) + Wqkv/Wr/Wo (TR) + Wih, r (row-major)
// -> split-swizzled u32[n][K] buffers. 2,228,224 octet-items total.
// ---------------------------------------------------------------------------
#define SEG0 1048576   // cat          (8192 x 128)
#define SEG1 1441792   // +Wqkv TR     (3072 x 128)
#define SEG2 1572864   // +Wr   TR     (1024 x 128)
#define SEG3 1703936   // +Wo   TR     (1024 x 128)
#define SEG4 2097152   // +Wih  row    (3072 x 128)
#define SEG5 2228224   // +r    row    (1024 x 128)

__global__ __launch_bounds__(256) void prep_all(
    const float* __restrict__ mem, const float* __restrict__ inputs,
    const float* __restrict__ Wqkv, const float* __restrict__ Wr,
    const float* __restrict__ Wo, const float* __restrict__ Wih,
    const float* __restrict__ r_in,
    unsigned* __restrict__ catP, unsigned* __restrict__ WqkvP,
    unsigned* __restrict__ WrP, unsigned* __restrict__ WoP,
    unsigned* __restrict__ WihP, unsigned* __restrict__ rP)
{
    int idx = blockIdx.x * 256 + threadIdx.x;
    if (idx >= SEG5) return;
    float x[8];
    if (idx < SEG0) {                       // cat gather, row-major read
        int c = idx & 127, n = idx >> 7;
        int kt = c >> 2, j = c & 3, k = kt * 32 + j * 8;
        const float* src = (n < 4096) ? (mem + (size_t)n * 1024 + k)
                                      : (inputs + (size_t)(n - 4096) * 1024 + k);
        float4 a = *(const float4*)src, b = *(const float4*)(src + 4);
        x[0]=a.x; x[1]=a.y; x[2]=a.z; x[3]=a.w; x[4]=b.x; x[5]=b.y; x[6]=b.z; x[7]=b.w;
        split_store8(x, catP, n, 1024, kt, j);
    } else if (idx < SEG3) {                // TR segments: W[k][n] -> [n][k]
        int i, Nr, ldw; const float* W; unsigned* out;
        if (idx < SEG1)      { i = idx - SEG0; Nr = 3072; ldw = 3072; W = Wqkv; out = WqkvP; }
        else if (idx < SEG2) { i = idx - SEG1; Nr = 1024; ldw = 1024; W = Wr;   out = WrP;  }
        else                 { i = idx - SEG2; Nr = 1024; ldw = 1024; W = Wo;   out = WoP;  }
        int n = i % Nr, c = i / Nr;
        int kt = c >> 2, j = c & 3, k = kt * 32 + j * 8;
        #pragma unroll
        for (int q = 0; q < 8; ++q) x[q] = W[(size_t)(k + q) * ldw + n];
        split_store8(x, out, n, 1024, kt, j);
    } else {                                // row-major: Wih, r
        int i; const float* W; unsigned* out;
        if (idx < SEG4) { i = idx - SEG3; W = Wih;  out = WihP; }
        else            { i = idx - SEG4; W = r_in; out = rP;   }
        int c = i & 127, n = i >> 7;
        int kt = c >> 2, j = c & 3, k = kt * 32 + j * 8;
        float4 a = *(const float4*)(W + (size_t)n * 1024 + k);
        float4 b = *(const float4*)(W + (size_t)n * 1024 + k + 4);
        x[0]=a.x; x[1]=a.y; x[2]=a.z; x[3]=a.w; x[4]=b.x; x[5]=b.y; x[6]=b.z; x[7]=b.w;
        split_store8(x, out, n, 1024, kt, j);
    }
}

// ---------------------------------------------------------------------------
// Split-bf16 MFMA GEMM, BOTH operands pre-split swizzled u32[rows][K], staged
// via global_load_lds width=16. 128x128 tile, BK=32, 256 threads (2x2 waves).
// SPLITOUT: write split-swizzled u32 output (via LDS bounce) instead of fp32.
// ---------------------------------------------------------------------------
template<bool BIAS, bool SPLITOUT>
__global__ __launch_bounds__(256) void gemm_pp(
    const uint4* __restrict__ Ap4, const uint4* __restrict__ Bp4,
    const float* __restrict__ bias, float* __restrict__ C,
    unsigned* __restrict__ Cp, int K, int ldc)
{
    __shared__ uint4 SH[2048];          // Ab = SH[0:1024), Bb = SH[1024:2048)
    uint4* Ab = SH;
    uint4* Bb = SH + 1024;
    int tid = threadIdx.x;
    int lane = tid & 63, wid = tid >> 6;
    int wr = wid >> 1, wc = wid & 1;
    int n0 = blockIdx.x * 128, m0 = blockIdx.y * 128;
    int r15 = lane & 15, s = lane >> 4;
    int r4 = (lane >> 4) * 4;
    int K4 = K >> 2;                     // row stride in uint4

    f32x4 acc[4][4];
    #pragma unroll
    for (int i = 0; i < 4; ++i)
        #pragma unroll
        for (int j = 0; j < 4; ++j) acc[i][j] = 0.0f;

    for (int kt = 0; kt < (K >> 5); ++kt) {
        #pragma unroll
        for (int q = 0; q < 4; ++q) {
            int base = q * 256 + wid * 64;      // wave-uniform LDS base
            int idx  = base + lane;             // per-lane element
            int row = idx >> 3, slot = idx & 7;
            gl_lds16(Ap4 + (size_t)(m0 + row) * K4 + kt * 8 + slot, &Ab[base]);
            gl_lds16(Bp4 + (size_t)(n0 + row) * K4 + kt * 8 + slot, &Bb[base]);
        }
        __syncthreads();   // vmcnt(0) drain: tiles landed
        FragU ahi[4], alo[4], bhi[4], blo[4];
        #pragma unroll
        for (int f = 0; f < 4; ++f) {
            int ar = wr * 64 + f * 16 + r15;
            ahi[f].u = Ab[ar * 8 + ((2 * s) ^ (ar & 7))];
            alo[f].u = Ab[ar * 8 + ((2 * s + 1) ^ (ar & 7))];
            int br = wc * 64 + f * 16 + r15;
            bhi[f].u = Bb[br * 8 + ((2 * s) ^ (br & 7))];
            blo[f].u = Bb[br * 8 + ((2 * s + 1) ^ (br & 7))];
        }
        #pragma unroll
        for (int fi = 0; fi < 4; ++fi)
            #pragma unroll
            for (int fj = 0; fj < 4; ++fj) {
                acc[fi][fj] = __builtin_amdgcn_mfma_f32_16x16x32_bf16(ahi[fi].h, bhi[fj].h, acc[fi][fj], 0, 0, 0);
                acc[fi][fj] = __builtin_amdgcn_mfma_f32_16x16x32_bf16(ahi[fi].h, blo[fj].h, acc[fi][fj], 0, 0, 0);
                acc[fi][fj] = __builtin_amdgcn_mfma_f32_16x16x32_bf16(alo[fi].h, bhi[fj].h, acc[fi][fj], 0, 0, 0);
            }
        __syncthreads();
    }

    if (!SPLITOUT) {
        #pragma unroll
        for (int fj = 0; fj < 4; ++fj) {
            int n = n0 + wc * 64 + fj * 16 + r15;
            float bv = BIAS ? bias[n] : 0.f;
            #pragma unroll
            for (int fi = 0; fi < 4; ++fi) {
                int m = m0 + wr * 64 + fi * 16 + r4;
                #pragma unroll
                for (int r = 0; r < 4; ++r)
                    C[(size_t)(m + r) * ldc + n] = acc[fi][fj][r] + bv;
            }
        }
    } else {
        float* Cs = (float*)SH;            // 64 x 128 fp32 = 32KB
        #pragma unroll
        for (int half = 0; half < 2; ++half) {
            __syncthreads();
            if (wr == half) {
                #pragma unroll
                for (int fi = 0; fi < 4; ++fi)
                    #pragma unroll
                    for (int fj = 0; fj < 4; ++fj)
                        #pragma unroll
                        for (int r = 0; r < 4; ++r)
                            Cs[(fi * 16 + r4 + r) * 128 + wc * 64 + fj * 16 + r15] = acc[fi][fj][r];
            }
            __syncthreads();
            #pragma unroll
            for (int q = 0; q < 4; ++q) {
                int oc = q * 256 + tid;
                int lr = oc >> 4, oct = oc & 15;
                float x[8];
                *(float4*)&x[0] = *(float4*)&Cs[lr * 128 + oct * 8];
                *(float4*)&x[4] = *(float4*)&Cs[lr * 128 + oct * 8 + 4];
                int m = m0 + half * 64 + lr;
                int k = n0 + oct * 8;
                split_store8(x, Cp, m, ldc, k >> 5, (k >> 3) & 3);
            }
        }
    }
}

// ---------------------------------------------------------------------------
// Fused TXL attention (fp32) with REGISTER online-softmax (m,l per-thread,
// shfl-reduced within 16-lane row groups; no serial sections, 2 barriers per
// j-tile). Writes y1 directly split-swizzled (y1P).
// ---------------------------------------------------------------------------
__global__ __launch_bounds__(256) void attn_fused(
    const float* __restrict__ qkv, const float* __restrict__ rk,
    const float* __restrict__ u_, const float* __restrict__ v_,
    unsigned* __restrict__ y1P)
{
    __shared__ float qu[64][68], qv[64][68], Kt[64][68], Vt[64][68];
    __shared__ float RKs[128][68];
    __shared__ float S[64][68];

    int tid = threadIdx.x;
    int it = blockIdx.x, b = blockIdx.y, h = blockIdx.z;
    int i0 = it * 64;
    int ti = tid >> 4, tj = tid & 15;

    {
        int r = tid >> 2, c0 = (tid & 3) * 16;
        size_t base = ((size_t)(i0 + r + 512) * 8 + b) * 3072 + h * 64;
        #pragma unroll
        for (int q = 0; q < 4; ++q) {
            int c = c0 + q * 4;
            float4 qq = *(const float4*)&qkv[base + c];
            float4 uu = *(const float4*)&u_[h * 64 + c];
            float4 vv = *(const float4*)&v_[h * 64 + c];
            *(float4*)&qu[r][c] = make_float4(qq.x + uu.x, qq.y + uu.y, qq.z + uu.z, qq.w + uu.w);
            *(float4*)&qv[r][c] = make_float4(qq.x + vv.x, qq.y + vv.y, qq.z + vv.z, qq.w + vv.w);
        }
    }

    float m[4] = {-1e30f, -1e30f, -1e30f, -1e30f};
    float l[4] = {0.f, 0.f, 0.f, 0.f};
    float Od[4][4] = {};
    int njt = it + 9;

    for (int jt = 0; jt < njt; ++jt) {
        int j0 = jt * 64;
        __syncthreads();   // staging buffers free (prev iter readers done)
        {
            int r = tid >> 2, c0 = (tid & 3) * 16;
            size_t kb = ((size_t)(j0 + r) * 8 + b) * 3072 + 1024 + h * 64;
            #pragma unroll
            for (int q = 0; q < 4; ++q) {
                int c = c0 + q * 4;
                *(float4*)&Kt[r][c] = *(const float4*)&qkv[kb + c];
                *(float4*)&Vt[r][c] = *(const float4*)&qkv[kb + 1024 + c];
            }
        }
        {
            int r2 = tid >> 1, c0 = (tid & 1) * 32;
            int jj = j0 - i0 + 448 + r2;
            jj = jj < 0 ? 0 : (jj > 1023 ? 1023 : jj);
            size_t rb = (size_t)jj * 1024 + h * 64;
            #pragma unroll
            for (int q = 0; q < 8; ++q) {
                int c = c0 + q * 4;
                *(float4*)&RKs[r2][c] = *(const float4*)&rk[rb + c];
            }
        }
        __syncthreads();

        float acc[4][4] = {};
        int jlb = (tj - ti) * 4 + 60;
        #pragma unroll 4
        for (int d4 = 0; d4 < 64; d4 += 4) {
            float4 Aq[4], Cq[4], Kv[4], Rv[7];
            #pragma unroll
            for (int i = 0; i < 4; ++i) {
                Aq[i] = *(float4*)&qu[ti * 4 + i][d4];
                Cq[i] = *(float4*)&qv[ti * 4 + i][d4];
                Kv[i] = *(float4*)&Kt[tj * 4 + i][d4];
            }
            #pragma unroll
            for (int t = 0; t < 7; ++t)
                Rv[t] = *(float4*)&RKs[jlb + t][d4];
            #pragma unroll
            for (int i = 0; i < 4; ++i)
                #pragma unroll
                for (int j = 0; j < 4; ++j) {
                    float4 kk = Kv[j];
                    float4 rr = Rv[j - i + 3];
                    acc[i][j] += Aq[i].x * kk.x + Aq[i].y * kk.y + Aq[i].z * kk.z + Aq[i].w * kk.w
                               + Cq[i].x * rr.x + Cq[i].y * rr.y + Cq[i].z * rr.z + Cq[i].w * rr.w;
                }
        }
        // scale + mask + register online-softmax (shfl reduce over 16-lane group)
        #pragma unroll
        for (int i = 0; i < 4; ++i) {
            int gi = i0 + ti * 4 + i;
            float mx = -1e30f;
            #pragma unroll
            for (int j = 0; j < 4; ++j) {
                int gj = j0 + tj * 4 + j;
                float vS = acc[i][j] * 0.125f;
                if (gj > gi + 512) vS = -1e30f;
                acc[i][j] = vS;
                mx = fmaxf(mx, vS);
            }
            mx = fmaxf(mx, __shfl_xor(mx, 1));
            mx = fmaxf(mx, __shfl_xor(mx, 2));
            mx = fmaxf(mx, __shfl_xor(mx, 4));
            mx = fmaxf(mx, __shfl_xor(mx, 8));
            float mn = fmaxf(m[i], mx);
            float sc = __expf(m[i] - mn);
            m[i] = mn;
            float4 pv;
            pv.x = __expf(acc[i][0] - mn);
            pv.y = __expf(acc[i][1] - mn);
            pv.z = __expf(acc[i][2] - mn);
            pv.w = __expf(acc[i][3] - mn);
            *(float4*)&S[ti * 4 + i][tj * 4] = pv;
            float ps = pv.x + pv.y + pv.z + pv.w;
            ps += __shfl_xor(ps, 1);
            ps += __shfl_xor(ps, 2);
            ps += __shfl_xor(ps, 4);
            ps += __shfl_xor(ps, 8);
            l[i] = l[i] * sc + ps;
            #pragma unroll
            for (int j2 = 0; j2 < 4; ++j2) Od[i][j2] *= sc;
        }
        // S rows of this 16-lane group written above, read below by the SAME
        // wave (DS ops per-wave in order); fence stops compiler reordering.
        asm volatile("" ::: "memory");
        #pragma unroll 4
        for (int jb = 0; jb < 64; jb += 4) {
            float4 p0 = *(float4*)&S[ti * 4 + 0][jb];
            float4 p1 = *(float4*)&S[ti * 4 + 1][jb];
            float4 p2 = *(float4*)&S[ti * 4 + 2][jb];
            float4 p3 = *(float4*)&S[ti * 4 + 3][jb];
            float4 v0 = *(float4*)&Vt[jb + 0][tj * 4];
            float4 v1 = *(float4*)&Vt[jb + 1][tj * 4];
            float4 v2 = *(float4*)&Vt[jb + 2][tj * 4];
            float4 v3 = *(float4*)&Vt[jb + 3][tj * 4];
            float4 pr[4] = {p0, p1, p2, p3};
            #pragma unroll
            for (int i = 0; i < 4; ++i) {
                Od[i][0] += pr[i].x * v0.x + pr[i].y * v1.x + pr[i].z * v2.x + pr[i].w * v3.x;
                Od[i][1] += pr[i].x * v0.y + pr[i].y * v1.y + pr[i].z * v2.y + pr[i].w * v3.y;
                Od[i][2] += pr[i].x * v0.z + pr[i].y * v1.z + pr[i].z * v2.z + pr[i].w * v3.z;
                Od[i][3] += pr[i].x * v0.w + pr[i].y * v1.w + pr[i].z * v2.w + pr[i].w * v3.w;
            }
        }
    }
    // epilogue: write split-swizzled y1P[n][k], n=(i0+ri)*8+b, k=h*64+tj*4..+3
    #pragma unroll
    for (int i = 0; i < 4; ++i) {
        int ri = ti * 4 + i;
        float inv = 1.f / l[i];
        float4 o = make_float4(Od[i][0] * inv, Od[i][1] * inv, Od[i][2] * inv, Od[i][3] * inv);
        int n = (i0 + ri) * 8 + b;
        unsigned hw0, hw1, lw0, lw1;
        split2(o.x, o.y, hw0, lw0);
        split2(o.z, o.w, hw1, lw1);
        int kt2 = 2 * h + (tj >> 3);
        int j2 = (tj >> 1) & 3;
        int wo = (tj & 1) * 2;
        unsigned* bp = y1P + (size_t)n * 1024 + kt2 * 32;
        *(uint2*)(bp + (((2 * j2)     ^ (n & 7)) * 4) + wo) = make_uint2(hw0, hw1);
        *(uint2*)(bp + (((2 * j2 + 1) ^ (n & 7)) * 4) + wo) = make_uint2(lw0, lw1);
    }
}

// ---------------------------------------------------------------------------
// Whh -> MFMA A-fragments, per-block contiguous:
// uint4 offset = g64*12288 + kt*384 + gate*128 + plane*64 + lane.
// (stays post-attention: output overlays the qkv region)
// ---------------------------------------------------------------------------
__global__ __launch_bounds__(256) void prep_whh(
    const float* __restrict__ Whh, uint4* __restrict__ outp)
{
    int idx = blockIdx.x * 256 + threadIdx.x;
    if (idx >= 393216) return;
    int lane = idx & 63;
    int rest = idx >> 6;
    int gate = rest % 3;
    int kt   = (rest / 3) & 31;
    int g64  = rest / 96;
    int n = gate * 1024 + g64 * 16 + (lane & 15);
    int k = kt * 32 + (lane >> 4) * 8;
    const float* src = Whh + (size_t)n * 1024 + k;
    float4 x0 = *(const float4*)src, x1 = *(const float4*)(src + 4);
    unsigned h[4], l[4];
    split2(x0.x, x0.y, h[0], l[0]);
    split2(x0.z, x0.w, h[1], l[1]);
    split2(x1.x, x1.y, h[2], l[2]);
    split2(x1.z, x1.w, h[3], l[3]);
    outp[((size_t)rest * 2 + 0) * 64 + lane] = make_uint4(h[0], h[1], h[2], h[3]);
    outp[((size_t)rest * 2 + 1) * 64 + lane] = make_uint4(l[0], l[1], l[2], l[3]);
}

// ---------------------------------------------------------------------------
// PERSISTENT GRU (r8 version, proven 6.75 us/step) — UNCHANGED.
// ---------------------------------------------------------------------------
__global__ __launch_bounds__(256, 1) void gru_persist2(
    const float* __restrict__ h0, float* __restrict__ hA, float* __restrict__ hB,
    const uint4* __restrict__ WhhG, const float* __restrict__ bhh,
    const float* __restrict__ xg, float* __restrict__ out,
    unsigned* __restrict__ flags)
{
    __shared__ uint4 Bf[4096];
    __shared__ float red[3][64][4];
    int tid = threadIdx.x;
    int lane = tid & 63, wv = tid >> 6;
    int g64 = blockIdx.x;

    int col = lane & 15;
    int d0 = g64 * 16 + (lane >> 4) * 4;
    bool act = (wv == 0) && (col < 8);
    float4 br4 = make_float4(0, 0, 0, 0), bz4 = br4, bn4 = br4;
    if (act) {
        br4 = *(const float4*)&bhh[d0];
        bz4 = *(const float4*)&bhh[1024 + d0];
        bn4 = *(const float4*)&bhh[2048 + d0];
    }
    const uint4* wb = WhhG + (size_t)g64 * 12288 + (wv < 3 ? wv : 0) * 128 + lane;

    for (int t = 0; t < 512; ++t) {
        const float* hi_ = (t == 0) ? h0 : ((t & 1) ? hA : hB);
        float* ho = (t & 1) ? hB : hA;

        float4 xr4, xz4, xn4;
        unsigned long long hp01 = 0, hp23 = 0;
        if (act) {
            size_t xb = ((size_t)t * 8 + col) * 3072 + d0;
            xr4 = *(const float4*)&xg[xb];
            xz4 = *(const float4*)&xg[xb + 1024];
            xn4 = *(const float4*)&xg[xb + 2048];
            hp01 = ld_coh64(hi_ + col * 1024 + d0);
            hp23 = ld_coh64(hi_ + col * 1024 + d0 + 2);
        }

        uint4 wA[16], wB[16];
        #pragma unroll
        for (int q = 0; q < 8; ++q) {
            wA[2 * q]     = wb[q * 384];
            wA[2 * q + 1] = wb[q * 384 + 64];
        }

        unsigned long long hq[16];
        #pragma unroll
        for (int i = 0; i < 4; ++i) {
            int s = i * 256 + tid;
            const float* hp = hi_ + (s & 7) * 1024 + (s >> 5) * 32 + ((s >> 3) & 3) * 8;
            #pragma unroll
            for (int q = 0; q < 4; ++q) hq[i * 4 + q] = ld_coh64(hp + q * 2);
        }
        #pragma unroll
        for (int i = 0; i < 4; ++i) {
            int s = i * 256 + tid;
            int b = s & 7, oct = (s >> 3) & 3, kt = s >> 5;
            float x[8];
            #pragma unroll
            for (int q = 0; q < 4; ++q) {
                x[2 * q]     = __uint_as_float((unsigned)(hq[i * 4 + q] & 0xffffffffu));
                x[2 * q + 1] = __uint_as_float((unsigned)(hq[i * 4 + q] >> 32));
            }
            unsigned hh[4], ll[4];
            split2(x[0], x[1], hh[0], ll[0]);
            split2(x[2], x[3], hh[1], ll[1]);
            split2(x[4], x[5], hh[2], ll[2]);
            split2(x[6], x[7], hh[3], ll[3]);
            int ln = oct * 16 + b;
            Bf[(kt * 2 + 0) * 64 + ln] = make_uint4(hh[0], hh[1], hh[2], hh[3]);
            Bf[(kt * 2 + 1) * 64 + ln] = make_uint4(ll[0], ll[1], ll[2], ll[3]);
        }
        __syncthreads();

        f32x4 acc = 0.0f;
        #define GRU_LOAD(dst, c0)                                   \
            _Pragma("unroll")                                       \
            for (int q = 0; q < 8; ++q) {                           \
                dst[2 * q]     = wb[((c0) * 8 + q) * 384];          \
                dst[2 * q + 1] = wb[((c0) * 8 + q) * 384 + 64];     \
            }
        #define GRU_COMP(src, c0)                                   \
            _Pragma("unroll")                                       \
            for (int q = 0; q < 8; ++q) {                           \
                int kt = (c0) * 8 + q;                              \
                FragU ah, al, bh, bl;                               \
                ah.u = src[2 * q]; al.u = src[2 * q + 1];           \
                bh.u = Bf[(kt * 2 + 0) * 64 + lane];                \
                bl.u = Bf[(kt * 2 + 1) * 64 + lane];                \
                acc = __builtin_amdgcn_mfma_f32_16x16x32_bf16(ah.h, bh.h, acc, 0, 0, 0); \
                acc = __builtin_amdgcn_mfma_f32_16x16x32_bf16(ah.h, bl.h, acc, 0, 0, 0); \
                acc = __builtin_amdgcn_mfma_f32_16x16x32_bf16(al.h, bh.h, acc, 0, 0, 0); \
            }
        if (wv < 3) {
            GRU_LOAD(wB, 1);
            GRU_COMP(wA, 0);
            GRU_LOAD(wA, 2);
            GRU_COMP(wB, 1);
            GRU_LOAD(wB, 3);
            GRU_COMP(wA, 2);
            GRU_COMP(wB, 3);
            *(f32x4*)&red[wv][lane][0] = acc;
        }
        #undef GRU_LOAD
        #undef GRU_COMP
        __syncthreads();

        if (act) {
            f32x4 aR = *(f32x4*)&red[0][lane][0];
            f32x4 aZ = *(f32x4*)&red[1][lane][0];
            f32x4 aN = *(f32x4*)&red[2][lane][0];
            float xr[4] = {xr4.x, xr4.y, xr4.z, xr4.w};
            float xz[4] = {xz4.x, xz4.y, xz4.z, xz4.w};
            float xn[4] = {xn4.x, xn4.y, xn4.z, xn4.w};
            float hp[4] = {__uint_as_float((unsigned)(hp01 & 0xffffffffu)),
                           __uint_as_float((unsigned)(hp01 >> 32)),
                           __uint_as_float((unsigned)(hp23 & 0xffffffffu)),
                           __uint_as_float((unsigned)(hp23 >> 32))};
            float br[4] = {br4.x, br4.y, br4.z, br4.w};
            float bz[4] = {bz4.x, bz4.y, bz4.z, bz4.w};
            float bn[4] = {bn4.x, bn4.y, bn4.z, bn4.w};
            float hn[4];
            #pragma unroll
            for (int r = 0; r < 4; ++r) {
                float rr = 1.f / (1.f + __expf(-(xr[r] + aR[r] + br[r])));
                float zz = 1.f / (1.f + __expf(-(xz[r] + aZ[r] + bz[r])));
                float nn = tanhf(xn[r] + rr * (aN[r] + bn[r]));
                hn[r] = (1.f - zz) * nn + zz * hp[r];
            }
            unsigned long long v01 = (unsigned long long)__float_as_uint(hn[0])
                                   | ((unsigned long long)__float_as_uint(hn[1]) << 32);
            unsigned long long v23 = (unsigned long long)__float_as_uint(hn[2])
                                   | ((unsigned long long)__float_as_uint(hn[3]) << 32);
            st_coh64(ho + col * 1024 + d0, v01);
            st_coh64(ho + col * 1024 + d0 + 2, v23);
            *(float4*)&out[((size_t)t * 8 + col) * 1024 + d0] =
                make_float4(hn[0], hn[1], hn[2], hn[3]);
        }

        if (t != 511) {
            __syncthreads();
            unsigned tgt = (unsigned)t + 1u;
            if (tid < 64) {
                if (tid == 0)
                    __hip_atomic_store(&flags[(size_t)g64 * 16], tgt,
                                       __ATOMIC_RELAXED, __HIP_MEMORY_SCOPE_AGENT);
                const unsigned* fp = &flags[(size_t)tid * 16];
                for (;;) {
                    unsigned f = __hip_atomic_load(fp, __ATOMIC_RELAXED,
                                                   __HIP_MEMORY_SCOPE_AGENT);
                    if (__all(f >= tgt)) break;
                }
            }
            __syncthreads();
        }
    }
}

// ---------------------------------------------------------------------------
// Fallback: one GRU step via MFMA (r7 kernel) if cooperative launch fails.
// ---------------------------------------------------------------------------
__global__ __launch_bounds__(192, 1) void gru_step_mfma(
    const float* __restrict__ hin, float* __restrict__ hout,
    const uint4* __restrict__ WhhG, const float* __restrict__ bhh,
    const float* __restrict__ xg, float* __restrict__ out, int t)
{
    __shared__ uint4 Bf[4096];
    __shared__ float red[3][64][4];
    int tid = threadIdx.x;
    int lane = tid & 63, wv = tid >> 6;
    int g64 = blockIdx.x;

    int col = lane & 15;
    int d0 = g64 * 16 + (lane >> 4) * 4;
    bool act = (wv == 0) && (col < 8);
    float4 xr4, xz4, xn4, hp4, br4, bz4, bn4;
    if (act) {
        size_t xb = ((size_t)t * 8 + col) * 3072 + d0;
        xr4 = *(const float4*)&xg[xb];
        xz4 = *(const float4*)&xg[xb + 1024];
        xn4 = *(const float4*)&xg[xb + 2048];
        hp4 = *(const float4*)&hin[col * 1024 + d0];
        br4 = *(const float4*)&bhh[d0];
        bz4 = *(const float4*)&bhh[1024 + d0];
        bn4 = *(const float4*)&bhh[2048 + d0];
    }

    const uint4* wb = WhhG + (size_t)g64 * 12288 + wv * 128 + lane;
    uint4 wA[16], wB[16];
    #pragma unroll
    for (int q = 0; q < 8; ++q) {
        wA[2 * q]     = wb[q * 384];
        wA[2 * q + 1] = wb[q * 384 + 64];
    }

    for (int s = tid; s < 1024; s += 192) {
        int b = s & 7, oct = (s >> 3) & 3, kt = s >> 5;
        const float* hp = hin + b * 1024 + kt * 32 + oct * 8;
        float4 x0 = *(const float4*)hp, x1 = *(const float4*)(hp + 4);
        unsigned hh[4], ll[4];
        split2(x0.x, x0.y, hh[0], ll[0]);
        split2(x0.z, x0.w, hh[1], ll[1]);
        split2(x1.x, x1.y, hh[2], ll[2]);
        split2(x1.z, x1.w, hh[3], ll[3]);
        int ln = oct * 16 + b;
        Bf[(kt * 2 + 0) * 64 + ln] = make_uint4(hh[0], hh[1], hh[2], hh[3]);
        Bf[(kt * 2 + 1) * 64 + ln] = make_uint4(ll[0], ll[1], ll[2], ll[3]);
    }
    __syncthreads();

    f32x4 acc = 0.0f;
    #define GRU_LOAD(dst, c0)                                   \
        _Pragma("unroll")                                       \
        for (int q = 0; q < 8; ++q) {                           \
            dst[2 * q]     = wb[((c0) * 8 + q) * 384];          \
            dst[2 * q + 1] = wb[((c0) * 8 + q) * 384 + 64];     \
        }
    #define GRU_COMP(src, c0)                                   \
        _Pragma("unroll")                                       \
        for (int q = 0; q < 8; ++q) {                           \
            int kt = (c0) * 8 + q;                              \
            FragU ah, al, bh, bl;                               \
            ah.u = src[2 * q]; al.u = src[2 * q + 1];           \
            bh.u = Bf[(kt * 2 + 0) * 64 + lane];                \
            bl.u = Bf[(kt * 2 + 1) * 64 + lane];                \
            acc = __builtin_amdgcn_mfma_f32_16x16x32_bf16(ah.h, bh.h, acc, 0, 0, 0); \
            acc = __builtin_amdgcn_mfma_f32_16x16x32_bf16(ah.h, bl.h, acc, 0, 0, 0); \
            acc = __builtin_amdgcn_mfma_f32_16x16x32_bf16(al.h, bh.h, acc, 0, 0, 0); \
        }
    GRU_LOAD(wB, 1);
    GRU_COMP(wA, 0);
    GRU_LOAD(wA, 2);
    GRU_COMP(wB, 1);
    GRU_LOAD(wB, 3);
    GRU_COMP(wA, 2);
    GRU_COMP(wB, 3);
    #undef GRU_LOAD
    #undef GRU_COMP

    *(f32x4*)&red[wv][lane][0] = acc;
    __syncthreads();

    if (act) {
        f32x4 aR = *(f32x4*)&red[0][lane][0];
        f32x4 aZ = *(f32x4*)&red[1][lane][0];
        f32x4 aN = *(f32x4*)&red[2][lane][0];
        float xr[4] = {xr4.x, xr4.y, xr4.z, xr4.w};
        float xz[4] = {xz4.x, xz4.y, xz4.z, xz4.w};
        float xn[4] = {xn4.x, xn4.y, xn4.z, xn4.w};
        float hp[4] = {hp4.x, hp4.y, hp4.z, hp4.w};
        float br[4] = {br4.x, br4.y, br4.z, br4.w};
        float bz[4] = {bz4.x, bz4.y, bz4.z, bz4.w};
        float bn[4] = {bn4.x, bn4.y, bn4.z, bn4.w};
        float hn[4];
        #pragma unroll
        for (int r = 0; r < 4; ++r) {
            float rr = 1.f / (1.f + __expf(-(xr[r] + aR[r] + br[r])));
            float zz = 1.f / (1.f + __expf(-(xz[r] + aZ[r] + bz[r])));
            float nn = tanhf(xn[r] + rr * (aN[r] + bn[r]));
            hn[r] = (1.f - zz) * nn + zz * hp[r];
        }
        float4 hv = make_float4(hn[0], hn[1], hn[2], hn[3]);
        *(float4*)&hout[col * 1024 + d0] = hv;
        *(float4*)&out[((size_t)t * 8 + col) * 1024 + d0] = hv;
    }
}

// ---------------------------------------------------------------------------
extern "C" void kernel_launch(void* const* d_in, const int* in_sizes, int n_in,
                              void* d_out, int out_size, void* d_ws, size_t ws_size,
                              hipStream_t stream) {
    (void)in_sizes; (void)n_in; (void)out_size; (void)ws_size;
    const float* inputs = (const float*)d_in[0];
    const float* r_in   = (const float*)d_in[1];
    const float* u_in   = (const float*)d_in[2];
    const float* v_in   = (const float*)d_in[3];
    const float* mem    = (const float*)d_in[4];
    const float* Wqkv   = (const float*)d_in[5];
    const float* Wr     = (const float*)d_in[6];
    const float* Wo     = (const float*)d_in[7];
    const float* Wih    = (const float*)d_in[8];
    const float* Whh    = (const float*)d_in[9];
    const float* bih    = (const float*)d_in[10];
    const float* bhh    = (const float*)d_in[11];
    const float* h0     = (const float*)d_in[12];
    float* out = (float*)d_out;
    float* ws = (float*)d_ws;

    float*    qkv   = ws;                           // [0, 25165824) — dead after attn
    float*    rk    = ws + 25165824;
    unsigned* y1P   = (unsigned*)(ws + 26214400);   // split y1, [4096][1024] u32
    unsigned* y2P   = (unsigned*)(ws + 30408704);   // split y2, [4096][1024] u32
    float*    xg    = ws + 34603008;                // catP/rP overlay (dead before xg write)
    float*    hA    = ws + 47185920;
    float*    hB    = ws + 47194112;
    unsigned* WqkvP = (unsigned*)(ws + 47202304);
    unsigned* WrP   = (unsigned*)(ws + 50348032);
    unsigned* WoP   = (unsigned*)(ws + 51396608);
    unsigned* WihP  = (unsigned*)(ws + 52445184);
    unsigned* flags = (unsigned*)(ws + 55590912);   // 64 flags x 64B
    uint4*    WhhG  = (uint4*)qkv;                  // written AFTER attn
    unsigned* catP  = (unsigned*)xg;                // [8192][1024] u32
    unsigned* rP    = (unsigned*)xg + 8388608;      // [1024][1024] u32

    dim3 blk(256);
    hipMemsetAsync(flags, 0, 4096, stream);   // zero flags EVERY launch (replay-safe)
    // ---- ONE fused prep pass (cat, Wqkv, Wr, Wo, Wih, r)
    prep_all<<<8704, blk, 0, stream>>>(mem, inputs, Wqkv, Wr, Wo, Wih, r_in,
                                       catP, WqkvP, WrP, WoP, WihP, rP);

    // ---- qkv GEMM, dead-Q-region split
    gemm_pp<false, false><<<dim3(16, 32), blk, 0, stream>>>(
        (const uint4*)catP, (const uint4*)WqkvP + 1024 * 256, nullptr,
        qkv + 1024, nullptr, 1024, 3072);
    gemm_pp<false, false><<<dim3(24, 32), blk, 0, stream>>>(
        (const uint4*)catP + 4096 * 256, (const uint4*)WqkvP, nullptr,
        qkv + (size_t)4096 * 3072, nullptr, 1024, 3072);
    // ---- rk = r @ W_r (now also gemm_pp)
    gemm_pp<false, false><<<dim3(8, 8), blk, 0, stream>>>(
        (const uint4*)rP, (const uint4*)WrP, nullptr, rk, nullptr, 1024, 1024);
    // ---- fused attention -> y1P (register softmax)
    attn_fused<<<dim3(8, 8, 16), blk, 0, stream>>>(qkv, rk, u_in, v_in, y1P);
    // ---- Whh fragment prep (qkv region now dead)
    prep_whh<<<1536, blk, 0, stream>>>(Whh, WhhG);
    // ---- y2P = (y1 @ W_o) split-swizzled directly
    gemm_pp<false, true><<<dim3(8, 32), blk, 0, stream>>>(
        (const uint4*)y1P, (const uint4*)WoP, nullptr, nullptr, y2P, 1024, 1024);
    // ---- xg = y2 @ W_ih^T + b_ih
    gemm_pp<true, false><<<dim3(24, 32), blk, 0, stream>>>(
        (const uint4*)y2P, (const uint4*)WihP, bih, xg, nullptr, 1024, 3072);

    // ---- GRU recurrence: persistent r8 kernel; fallback: 512 launches
    {
        const float* a0 = h0; float* a1 = hA; float* a2 = hB;
        const uint4* a3 = WhhG; const float* a4 = bhh; const float* a5 = xg;
        float* a6 = out; unsigned* a7 = flags;
        void* args[8] = {&a0, &a1, &a2, &a3, &a4, &a5, &a6, &a7};
        hipError_t e = hipLaunchCooperativeKernel((void*)gru_persist2,
                                                  dim3(64), dim3(256), args, 0, stream);
        if (e != hipSuccess) {
            const float* hin = h0;
            for (int s = 0; s < 512; ++s) {
                float* hp = (s & 1) ? hB : hA;
                gru_step_mfma<<<64, dim3(192), 0, stream>>>(hin, hp, WhhG, bhh, xg, out, s);
                hin = hp;
            }
        }
    }
}